// Round 3
// baseline (450.969 us; speedup 1.0000x reference)
//
#include <hip/hip_runtime.h>
#include <math.h>

#define Bq 8
#define Lq 16384
#define Hq 64
#define N2q 32
#define NLAYERSq 5

#define STH 512              // scan kernel threads per WG
#define NGR (STH/4)          // 128 chunks per (b,h)
#define LCq (Lq/NGR)         // 128 steps per chunk

typedef float v2f __attribute__((ext_vector_type(2)));

// Genuine packed-f32 ops (double-rate on CDNA). The ext_vector_type(2)
// operands map to even-aligned VGPR pairs; VOP3P v_pk_* is per-component.
__device__ __forceinline__ v2f pk_fma(v2f a, v2f b, v2f c) {
    v2f d;
    asm("v_pk_fma_f32 %0, %1, %2, %3" : "=v"(d) : "v"(a), "v"(b), "v"(c));
    return d;
}
__device__ __forceinline__ v2f pk_mul(v2f a, v2f b) {
    v2f d;
    asm("v_pk_mul_f32 %0, %1, %2" : "=v"(d) : "v"(a), "v"(b));
    return d;
}

__device__ __forceinline__ float fast_tanh(float y) {
    float e = __expf(2.0f * y);
    return 1.0f - 2.0f * __builtin_amdgcn_rcpf(e + 1.0f);
}

// ---------------------------------------------------------------------------
// K1: u[b,h,l] = tanh( 20*log10(|x[b,l]|+eps) * w_in[h] + b_in[h] )
// ---------------------------------------------------------------------------
__global__ __launch_bounds__(256)
void k_input(const float* __restrict__ x, const float* __restrict__ w_in,
             const float* __restrict__ b_in, float* __restrict__ u) {
    int idx = blockIdx.x * 256 + threadIdx.x;       // over B*H*L, l fastest
    int l  = idx & (Lq - 1);
    int bh = idx >> 14;
    int h  = bh & (Hq - 1);
    int b  = bh >> 6;
    float xv = x[(b << 14) + l];
    float s  = 6.0205999132796239f * __log2f(fabsf(xv) + 1e-5f); // 20*log10
    u[idx] = fast_tanh(fmaf(s, w_in[h], b_in[h]));
}

// ---------------------------------------------------------------------------
// K2: DSSM scan + tanh.  One WG per (b,h). Two-sweep chunk-parallel scan.
// Modes packed in pairs (v2f); inner loops are forced v_pk_fma_f32.
// ---------------------------------------------------------------------------
__global__ __launch_bounds__(STH)
void k_scan(const float* __restrict__ uin, float* __restrict__ uout,
            const float* __restrict__ log_dt, const float* __restrict__ log_A_real,
            const float* __restrict__ A_imag, const float* __restrict__ C_re,
            const float* __restrict__ C_im, const float* __restrict__ Dvec,
            int layer) {
    __shared__ float mw[N2q][2];    // w = exp(dtA)
    __shared__ float mc[N2q][2];    // 2 * C*(exp(dtA)-1)/A   (factor 2 folded)
    __shared__ float mwL[N2q][2];   // w^LC
    __shared__ float st[NGR][N2q][2];

    const int bh  = blockIdx.x;
    const int h   = bh & (Hq - 1);
    const int tid = threadIdx.x;

    if (tid < N2q) {
        int n = tid;
        int pidx = (layer * Hq + h) * N2q + n;
        double dt  = exp((double)log_dt[layer * Hq + h]);
        double aRe = -exp((double)log_A_real[pidx]);
        double aIm = (double)A_imag[pidx];
        double dAr = aRe * dt, dAi = aIm * dt;
        double er  = exp(dAr);
        double wre = er * cos(dAi), wim = er * sin(dAi);
        double Er  = wre - 1.0, Ei = wim;          // exp(dtA)-1
        double inv = 1.0 / (aRe * aRe + aIm * aIm);
        double Fr  = (Er * aRe + Ei * aIm) * inv;  // (exp(dtA)-1)/A
        double Fi  = (Ei * aRe - Er * aIm) * inv;
        double Cr  = (double)C_re[pidx], Ci = (double)C_im[pidx];
        mw[n][0] = (float)wre;            mw[n][1] = (float)wim;
        mc[n][0] = (float)(2.0 * (Cr * Fr - Ci * Fi));
        mc[n][1] = (float)(2.0 * (Cr * Fi + Ci * Fr));
        double eL  = exp(dAr * (double)LCq);
        double phL = dAi * (double)LCq;
        mwL[n][0] = (float)(eL * cos(phL));
        mwL[n][1] = (float)(eL * sin(phL));
    }
    __syncthreads();

    const int g = tid >> 2;     // chunk id (0..127)
    const int r = tid & 3;      // mode sub-group: modes r*8 .. r*8+7 (4 pairs)

    v2f wR[4], wI[4], wIn[4], cR[4], cIn[4], sR[4], sI[4];
    #pragma unroll
    for (int p = 0; p < 4; p++) {
        int n0 = (r << 3) | (p << 1);
        wR[p]  = (v2f){mw[n0][0], mw[n0 + 1][0]};
        wI[p]  = (v2f){mw[n0][1], mw[n0 + 1][1]};
        wIn[p] = -wI[p];
        cR[p]  = (v2f){mc[n0][0], mc[n0 + 1][0]};
        cIn[p] = (v2f){-mc[n0][1], -mc[n0 + 1][1]};
        sR[p]  = (v2f){0.f, 0.f};
        sI[p]  = (v2f){0.f, 0.f};
    }

    const float* up = uin + ((size_t)bh << 14) + (g << 7);

    // ---- sweep 1: zero-init local chunk scan -> final states ----
    for (int i = 0; i < LCq; i += 4) {
        float4 u4 = *(const float4*)(up + i);
        float uu[4] = {u4.x, u4.y, u4.z, u4.w};
        #pragma unroll
        for (int k = 0; k < 4; k++) {
            v2f uvv = (v2f){uu[k], uu[k]};
            #pragma unroll
            for (int p = 0; p < 4; p++) {
                v2f t  = pk_fma(wIn[p], sI[p], uvv);
                v2f tI = pk_mul(wI[p], sR[p]);
                sR[p] = pk_fma(wR[p], sR[p], t);
                sI[p] = pk_fma(wR[p], sI[p], tI);
            }
        }
    }
    #pragma unroll
    for (int p = 0; p < 4; p++) {
        int n0 = (r << 3) | (p << 1);
        st[g][n0][0]     = sR[p].x; st[g][n0][1]     = sI[p].x;
        st[g][n0 + 1][0] = sR[p].y; st[g][n0 + 1][1] = sI[p].y;
    }
    __syncthreads();

    // ---- cross-chunk serial scan (32 lanes, in-place: slot j becomes S_j) ----
    if (tid < N2q) {
        int n = tid;
        float wLr = mwL[n][0], wLi = mwL[n][1];
        float Sr = 0.f, Si = 0.f;
        float fr = st[0][n][0], fi = st[0][n][1];
        #pragma unroll 4
        for (int j = 0; j < NGR; j++) {
            float fr2 = 0.f, fi2 = 0.f;
            if (j + 1 < NGR) { fr2 = st[j + 1][n][0]; fi2 = st[j + 1][n][1]; }
            st[j][n][0] = Sr; st[j][n][1] = Si;
            float nSr = fmaf(wLr, Sr, fmaf(-wLi, Si, fr));
            Si = fmaf(wLr, Si, fmaf(wLi, Sr, fi));
            Sr = nSr;
            fr = fr2; fi = fi2;
        }
    }
    __syncthreads();

    // ---- sweep 2: replay with true initial state, emit tanh(y) ----
    #pragma unroll
    for (int p = 0; p < 4; p++) {
        int n0 = (r << 3) | (p << 1);
        sR[p] = (v2f){st[g][n0][0], st[g][n0 + 1][0]};
        sI[p] = (v2f){st[g][n0][1], st[g][n0 + 1][1]};
    }
    const float Du = Dvec[layer * Hq + h];
    float* yp = uout + ((size_t)bh << 14) + (g << 7);

    for (int i = 0; i < LCq; i += 4) {
        float4 u4 = *(const float4*)(up + i);
        float uu[4] = {u4.x, u4.y, u4.z, u4.w};
        float o4[4];
        #pragma unroll
        for (int k = 0; k < 4; k++) {
            v2f uvv = (v2f){uu[k], uu[k]};
            v2f accP = (v2f){0.f, 0.f};
            #pragma unroll
            for (int p = 0; p < 4; p++) {
                v2f t  = pk_fma(wIn[p], sI[p], uvv);
                v2f tI = pk_mul(wI[p], sR[p]);
                sR[p] = pk_fma(wR[p], sR[p], t);
                sI[p] = pk_fma(wR[p], sI[p], tI);
                accP = pk_fma(cR[p],  sR[p], accP);
                accP = pk_fma(cIn[p], sI[p], accP);
            }
            float acc = accP.x + accP.y;   // 2x already folded into c
            acc += __shfl_xor(acc, 1);     // sum 32 modes across the 4-lane group
            acc += __shfl_xor(acc, 2);
            o4[k] = fast_tanh(fmaf(Du, uu[k], acc));
        }
        if (r == 0) {
            *(float4*)(yp + i) = make_float4(o4[0], o4[1], o4[2], o4[3]);
        }
    }
}

// ---------------------------------------------------------------------------
// K3: channel-major linear + tanh: out[b,o,l] = tanh(b[o] + sum_h W[o,h]*u[b,h,l])
// ---------------------------------------------------------------------------
__global__ __launch_bounds__(256)
void k_linear(const float* __restrict__ uin, const float* __restrict__ W,
              const float* __restrict__ bias, float* __restrict__ uout) {
    __shared__ float Wt[64][68];   // transposed: Wt[h][o]
    __shared__ float Ut[64][64];   // Ut[h][ll]
    const int b  = blockIdx.y;
    const int l0 = blockIdx.x * 64;
    const int tid = threadIdx.x;

    for (int idx = tid; idx < 4096; idx += 256) {
        int o = idx >> 6, hh = idx & 63;
        Wt[hh][o] = W[idx];
        Ut[o][hh] = uin[(((size_t)(b << 6) | o) << 14) + l0 + hh];
    }
    __syncthreads();

    float acc[4][4];
    #pragma unroll
    for (int j = 0; j < 4; j++)
        #pragma unroll
        for (int k = 0; k < 4; k++) acc[j][k] = 0.f;

    const int og = (tid >> 4) << 2;
    const int lg = (tid & 15) << 2;

    #pragma unroll 4
    for (int hh = 0; hh < 64; ++hh) {
        float4 wv = *(const float4*)&Wt[hh][og];
        float4 uv = *(const float4*)&Ut[hh][lg];
        acc[0][0] = fmaf(wv.x, uv.x, acc[0][0]); acc[0][1] = fmaf(wv.x, uv.y, acc[0][1]);
        acc[0][2] = fmaf(wv.x, uv.z, acc[0][2]); acc[0][3] = fmaf(wv.x, uv.w, acc[0][3]);
        acc[1][0] = fmaf(wv.y, uv.x, acc[1][0]); acc[1][1] = fmaf(wv.y, uv.y, acc[1][1]);
        acc[1][2] = fmaf(wv.y, uv.z, acc[1][2]); acc[1][3] = fmaf(wv.y, uv.w, acc[1][3]);
        acc[2][0] = fmaf(wv.z, uv.x, acc[2][0]); acc[2][1] = fmaf(wv.z, uv.y, acc[2][1]);
        acc[2][2] = fmaf(wv.z, uv.z, acc[2][2]); acc[2][3] = fmaf(wv.z, uv.w, acc[2][3]);
        acc[3][0] = fmaf(wv.w, uv.x, acc[3][0]); acc[3][1] = fmaf(wv.w, uv.y, acc[3][1]);
        acc[3][2] = fmaf(wv.w, uv.z, acc[3][2]); acc[3][3] = fmaf(wv.w, uv.w, acc[3][3]);
    }

    #pragma unroll
    for (int j = 0; j < 4; j++) {
        float bo = bias[og + j];
        float4 o4;
        o4.x = fast_tanh(acc[j][0] + bo);
        o4.y = fast_tanh(acc[j][1] + bo);
        o4.z = fast_tanh(acc[j][2] + bo);
        o4.w = fast_tanh(acc[j][3] + bo);
        *(float4*)&uout[(((size_t)(b << 6) | (og + j)) << 14) + l0 + lg] = o4;
    }
}

// ---------------------------------------------------------------------------
// K4: out[b,l] = x[b,l] * 10^((sum_h w_out[h]*u[b,h,l] + b_out)/20)
// ---------------------------------------------------------------------------
__global__ __launch_bounds__(256)
void k_out(const float* __restrict__ u, const float* __restrict__ x,
           const float* __restrict__ w_out, const float* __restrict__ b_out,
           float* __restrict__ out) {
    int idx = blockIdx.x * 256 + threadIdx.x;   // over B*L
    int b = idx >> 14;
    int l = idx & (Lq - 1);
    const float* up = u + ((size_t)b << 20) + l;
    float acc = 0.f;
    #pragma unroll 8
    for (int hh = 0; hh < 64; ++hh)
        acc = fmaf(w_out[hh], up[(size_t)hh << 14], acc);
    float g = acc + b_out[0];
    out[idx] = x[idx] * exp2f(g * 0.16609640474436812f);  // log2(10)/20
}

// ---------------------------------------------------------------------------
extern "C" void kernel_launch(void* const* d_in, const int* in_sizes, int n_in,
                              void* d_out, int out_size, void* d_ws, size_t ws_size,
                              hipStream_t stream) {
    const float* x          = (const float*)d_in[0];
    const float* w_in       = (const float*)d_in[1];
    const float* b_in       = (const float*)d_in[2];
    const float* w_mid      = (const float*)d_in[3];
    const float* b_mid      = (const float*)d_in[4];
    const float* w_out      = (const float*)d_in[5];
    const float* b_out      = (const float*)d_in[6];
    const float* log_dt     = (const float*)d_in[7];
    const float* log_A_real = (const float*)d_in[8];
    const float* A_imag     = (const float*)d_in[9];
    const float* C_re       = (const float*)d_in[10];
    const float* C_im       = (const float*)d_in[11];
    const float* Dv         = (const float*)d_in[12];

    float* u0 = (float*)d_ws;
    float* u1 = u0 + (size_t)Bq * Hq * Lq;
    float* out = (float*)d_out;

    k_input<<<(Bq * Hq * Lq) / 256, 256, 0, stream>>>(x, w_in, b_in, u0);
    k_scan<<<Bq * Hq, STH, 0, stream>>>(u0, u1, log_dt, log_A_real, A_imag,
                                        C_re, C_im, Dv, 0);
    for (int i = 0; i < 4; i++) {
        k_linear<<<dim3(Lq / 64, Bq), 256, 0, stream>>>(
            u1, w_mid + (size_t)i * Hq * Hq, b_mid + (size_t)i * Hq, u0);
        k_scan<<<Bq * Hq, STH, 0, stream>>>(u0, u1, log_dt, log_A_real, A_imag,
                                            C_re, C_im, Dv, i + 1);
    }
    k_out<<<(Bq * Lq) / 256, 256, 0, stream>>>(u1, x, w_out, b_out, out);
}

// Round 4
// 327.668 us; speedup vs baseline: 1.3763x; 1.3763x over previous
//
#include <hip/hip_runtime.h>
#include <math.h>

#define Bq 8
#define Lq 16384
#define Hq 64
#define N2q 32
#define NLAYERSq 5

typedef short  bf16x8 __attribute__((ext_vector_type(8)));
typedef float  f32x4  __attribute__((ext_vector_type(4)));

#define MFMA16(a, b, c) __builtin_amdgcn_mfma_f32_16x16x32_bf16(a, b, c, 0, 0, 0)

// ---- LDS layout for k_scan (dynamic) ----
#define UTH_OFF   0           // ushort [128][192]  48 KB  (bf16-hi of [U | S])
#define UTL_OFF   49152       // ushort [128][192]  48 KB  (bf16-lo)
#define SF_OFF    98304       // float  [64][130]   33.28 KB
#define SUB_OFF   131584      // float  [8][32][2]  2 KB
#define SMEM_SZ   133632
#define YST_OFF   0           // float [128][132] overlays UTh/UTl after GEMM2

// ---- workspace layout (bytes) ----
#define WT_OFF_B   0                       // f32 [320][32][4]
#define WP_OFF_B   163840                  // ushort [320][64][128]
#define A2_OFF_B   (163840 + 5242880)      // ushort [320][128][192]
#define U_OFF_B    (163840 + 5242880 + 15728640)   // f32 [512][16384]

__device__ __forceinline__ unsigned short f2bf(float f) {
    union { float f; unsigned int u; } v; v.f = f;
    unsigned int r = v.u + 0x7FFF + ((v.u >> 16) & 1);
    return (unsigned short)(r >> 16);
}
__device__ __forceinline__ float bf2f(unsigned short h) {
    union { unsigned int u; float f; } v; v.u = ((unsigned int)h) << 16;
    return v.f;
}
__device__ __forceinline__ float fast_tanh(float y) {
    float e = __expf(2.0f * y);
    return 1.0f - 2.0f * __builtin_amdgcn_rcpf(e + 1.0f);
}

// ---------------------------------------------------------------------------
// k_prep: per (layer,h) coefficient tables in f64 -> bf16/f32.
//   Wp [64][128]  : rows kk<32 Re(w^{127-l}), kk>=32 Im(w^{127-l})
//   A2 [128][192] : cols 0..127 Toeplitz K[m-k] (K[0] += D); cols 128..191 E
//   wT_tab [32][4]: (wT.re, wT.im, wT16.re, wT16.im), wT = w^128, wT16 = wT^16
// ---------------------------------------------------------------------------
__global__ __launch_bounds__(64)
void k_prep(const float* __restrict__ log_dt, const float* __restrict__ log_A_real,
            const float* __restrict__ A_imag, const float* __restrict__ C_re,
            const float* __restrict__ C_im, const float* __restrict__ Dvec,
            float* __restrict__ wT_tab, unsigned short* __restrict__ Wp,
            unsigned short* __restrict__ A2) {
    __shared__ float P[129][32][2];
    __shared__ float cre[32], cim[32], Kv[128];
    const int ph = blockIdx.x;          // layer*64 + h
    const int layer = ph >> 6, h = ph & 63;
    const int tid = threadIdx.x;

    if (tid < 32) {
        int n = tid;
        int pidx = ph * N2q + n;
        double dt  = exp((double)log_dt[ph]);
        double aRe = -exp((double)log_A_real[pidx]);
        double aIm = (double)A_imag[pidx];
        double dAr = aRe * dt, dAi = aIm * dt;
        double er  = exp(dAr);
        double wre = er * cos(dAi), wim = er * sin(dAi);
        // c = 2 * C * (exp(dtA)-1)/A
        double Er = wre - 1.0, Ei = wim;
        double inv = 1.0 / (aRe * aRe + aIm * aIm);
        double Fr = (Er * aRe + Ei * aIm) * inv;
        double Fi = (Ei * aRe - Er * aIm) * inv;
        double Cr = (double)C_re[pidx], Ci = (double)C_im[pidx];
        cre[n] = (float)(2.0 * (Cr * Fr - Ci * Fi));
        cim[n] = (float)(2.0 * (Cr * Fi + Ci * Fr));
        // powers w^0..w^128
        double pr = 1.0, pi = 0.0;
        for (int j = 0; j <= 128; j++) {
            P[j][n][0] = (float)pr; P[j][n][1] = (float)pi;
            double npr = pr * wre - pi * wim;
            pi = pr * wim + pi * wre; pr = npr;
        }
        // wT = w^128 (= current p after loop? p is w^129 now; use P[128])
        double tr = (double)P[128][n][0], ti = (double)P[128][n][1];
        // recompute exactly in f64: tr,ti hold f32-rounded; acceptable (f32 path)
        float wTr = P[128][n][0], wTi = P[128][n][1];
        // wT16 = wT^16 via 4 squarings (f64 from f32 inputs)
        double qr = tr, qi = ti;
        for (int s = 0; s < 4; s++) {
            double nr = qr * qr - qi * qi;
            qi = 2.0 * qr * qi; qr = nr;
        }
        float* wt = wT_tab + ph * 128 + n * 4;
        wt[0] = wTr; wt[1] = wTi; wt[2] = (float)qr; wt[3] = (float)qi;
    }
    __syncthreads();
    // K[d]
    for (int d = tid; d < 128; d += 64) {
        float s = 0.f;
        for (int n = 0; n < 32; n++)
            s += cre[n] * P[d][n][0] - cim[n] * P[d][n][1];
        if (d == 0) s += Dvec[ph];
        Kv[d] = s;
    }
    __syncthreads();
    // Wp
    unsigned short* wpb = Wp + (size_t)ph * 8192;
    for (int e = tid; e < 8192; e += 64) {
        int kk = e >> 7, l = e & 127;
        float v = (kk < 32) ? P[127 - l][kk][0] : P[127 - l][kk - 32][1];
        wpb[e] = f2bf(v);
    }
    // A2
    unsigned short* a2b = A2 + (size_t)ph * 24576;
    for (int e = tid; e < 24576; e += 64) {
        int m = e / 192, k = e - m * 192;
        float v;
        if (k < 128) {
            v = (k <= m) ? Kv[m - k] : 0.f;
        } else {
            int kk = k - 128, n2 = kk & 31;
            float pr = P[m + 1][n2][0], pi = P[m + 1][n2][1];
            v = (kk < 32) ? (cre[n2] * pr - cim[n2] * pi)
                          : -(cre[n2] * pi + cim[n2] * pr);
        }
        a2b[e] = f2bf(v);
    }
}

// ---------------------------------------------------------------------------
// k_input: u[b,h,l] = tanh( 20*log10(|x[b,l]|+eps) * w_in[h] + b_in[h] )
// ---------------------------------------------------------------------------
__global__ __launch_bounds__(256)
void k_input(const float* __restrict__ x, const float* __restrict__ w_in,
             const float* __restrict__ b_in, float* __restrict__ u) {
    int idx = blockIdx.x * 256 + threadIdx.x;
    int l  = idx & (Lq - 1);
    int bh = idx >> 14;
    int h  = bh & (Hq - 1);
    int b  = bh >> 6;
    float xv = x[(b << 14) + l];
    float s  = 6.0205999132796239f * __log2f(fabsf(xv) + 1e-5f);
    u[idx] = fast_tanh(fmaf(s, w_in[h], b_in[h]));
}

// ---------------------------------------------------------------------------
// k_scan: MFMA DSSM layer, in-place on u[bh][16384]. One WG (256 thr) per bh.
// ---------------------------------------------------------------------------
__global__ __launch_bounds__(256)
void k_scan(float* __restrict__ u, const unsigned short* __restrict__ Wp_all,
            const unsigned short* __restrict__ A2_all,
            const float* __restrict__ wT_all, int layer) {
    extern __shared__ char smem[];
    unsigned short* UTh = (unsigned short*)(smem + UTH_OFF);
    unsigned short* UTl = (unsigned short*)(smem + UTL_OFF);
    float* Sf  = (float*)(smem + SF_OFF);    // [64][130]
    float* sub = (float*)(smem + SUB_OFF);   // [8][32][2]
    float* yst = (float*)(smem + YST_OFF);   // [128][132] overlay

    const int bh = blockIdx.x;
    const int h  = bh & 63;
    const int tid = threadIdx.x;
    const int lane = tid & 63;
    const int wave = tid >> 6;
    const int ph = layer * 64 + h;
    const unsigned short* Wp = Wp_all + (size_t)ph * 8192;
    const unsigned short* A2 = A2_all + (size_t)ph * 24576;
    const float* wT4 = wT_all + ph * 128;
    float* uu = u + ((size_t)bh << 14);

    const int rA = lane & 15;     // fragment row index
    const int qA = lane >> 4;     // fragment k-group

    // ---- stage u -> UTh/UTl (bf16 hi/lo), XOR-swizzled ----
    for (int it = 0; it < 8; ++it) {
        int flat8 = (it * 256 + tid) * 8;
        int n = flat8 >> 7;        // chunk
        int k = flat8 & 127;       // pos in chunk
        float4 a = *(const float4*)(uu + flat8);
        float4 b = *(const float4*)(uu + flat8 + 4);
        float f[8] = {a.x, a.y, a.z, a.w, b.x, b.y, b.z, b.w};
        bf16x8 hi, lo;
        #pragma unroll
        for (int j = 0; j < 8; j++) {
            unsigned short hb = f2bf(f[j]);
            hi[j] = (short)hb;
            lo[j] = (short)f2bf(f[j] - bf2f(hb));
        }
        int kb = (k * 2) ^ ((n & 7) << 4);
        *(bf16x8*)((char*)UTh + n * 384 + kb) = hi;
        *(bf16x8*)((char*)UTl + n * 384 + kb) = lo;
    }
    __syncthreads();

    // ---- GEMM1: Sf[64][128] = Wp . U  (2-pass: B = Uh + Ul) ----
    {
        f32x4 acc1[8];
        #pragma unroll
        for (int nt = 0; nt < 8; nt++) acc1[nt] = (f32x4){0.f, 0.f, 0.f, 0.f};
        const int mt1 = wave;   // rows 16*wave..16*wave+15
        for (int ks = 0; ks < 4; ks++) {
            bf16x8 af = *(const bf16x8*)(Wp + (mt1 * 16 + rA) * 128 + ks * 32 + qA * 8);
            #pragma unroll
            for (int nt = 0; nt < 8; nt++) {
                int n = nt * 16 + rA;
                int kb = (ks * 64 + qA * 16) ^ ((n & 7) << 4);
                bf16x8 bhv = *(const bf16x8*)((char*)UTh + n * 384 + kb);
                bf16x8 blv = *(const bf16x8*)((char*)UTl + n * 384 + kb);
                acc1[nt] = MFMA16(af, bhv, acc1[nt]);
                acc1[nt] = MFMA16(af, blv, acc1[nt]);
            }
        }
        #pragma unroll
        for (int nt = 0; nt < 8; nt++) {
            int c = nt * 16 + rA;
            #pragma unroll
            for (int r = 0; r < 4; r++)
                Sf[(mt1 * 16 + qA * 4 + r) * 130 + c] = acc1[nt][r];
        }
    }
    __syncthreads();

    // ---- hierarchical cross-chunk scan: Sf (local finals) -> Sf (init states)
    const int  sn = tid & 31;       // mode
    const int  ss = tid >> 5;       // sub-block (16 chunks each)
    const float wTr = wT4[sn * 4 + 0], wTi = wT4[sn * 4 + 1];
    {
        float fr[16], fi[16];
        #pragma unroll
        for (int i = 0; i < 16; i++) {
            fr[i] = Sf[sn * 130 + ss * 16 + i];
            fi[i] = Sf[(sn + 32) * 130 + ss * 16 + i];
        }
        float Fr = 0.f, Fi = 0.f;
        #pragma unroll
        for (int i = 0; i < 16; i++) {
            float nFr = fmaf(wTr, Fr, fmaf(-wTi, Fi, fr[i]));
            Fi = fmaf(wTr, Fi, fmaf(wTi, Fr, fi[i]));
            Fr = nFr;
        }
        sub[(ss * 32 + sn) * 2 + 0] = Fr;
        sub[(ss * 32 + sn) * 2 + 1] = Fi;
    }
    __syncthreads();
    if (tid < 32) {
        float w16r = wT4[tid * 4 + 2], w16i = wT4[tid * 4 + 3];
        float Gr = 0.f, Gi = 0.f;
        for (int s = 0; s < 8; s++) {
            float tr = sub[(s * 32 + tid) * 2 + 0];
            float ti = sub[(s * 32 + tid) * 2 + 1];
            sub[(s * 32 + tid) * 2 + 0] = Gr;
            sub[(s * 32 + tid) * 2 + 1] = Gi;
            float nGr = fmaf(w16r, Gr, fmaf(-w16i, Gi, tr));
            Gi = fmaf(w16r, Gi, fmaf(w16i, Gr, ti));
            Gr = nGr;
        }
    }
    __syncthreads();
    {
        float fr[16], fi[16];
        #pragma unroll
        for (int i = 0; i < 16; i++) {
            fr[i] = Sf[sn * 130 + ss * 16 + i];
            fi[i] = Sf[(sn + 32) * 130 + ss * 16 + i];
        }
        float Fr = sub[(ss * 32 + sn) * 2 + 0];
        float Fi = sub[(ss * 32 + sn) * 2 + 1];
        #pragma unroll
        for (int i = 0; i < 16; i++) {
            Sf[sn * 130 + ss * 16 + i] = Fr;          // T_init[c]
            Sf[(sn + 32) * 130 + ss * 16 + i] = Fi;
            float nFr = fmaf(wTr, Fr, fmaf(-wTi, Fi, fr[i]));
            Fi = fmaf(wTr, Fi, fmaf(wTi, Fr, fi[i]));
            Fr = nFr;
        }
    }
    __syncthreads();

    // ---- convert T_init -> UT S-region (bf16 hi/lo, swizzled) ----
    for (int e = tid; e < 8192; e += 256) {
        int kk = e >> 7, c = e & 127;
        float v = Sf[kk * 130 + c];
        unsigned short hb = f2bf(v);
        unsigned short lb = f2bf(v - bf2f(hb));
        int kb = (256 + kk * 2) ^ ((c & 7) << 4);
        *(unsigned short*)((char*)UTh + c * 384 + kb) = hb;
        *(unsigned short*)((char*)UTl + c * 384 + kb) = lb;
    }
    __syncthreads();

    // ---- GEMM2: Y[128][128] = A2[128][192] . [U; S] ----
    f32x4 acc[2][8];
    #pragma unroll
    for (int mi = 0; mi < 2; mi++)
        #pragma unroll
        for (int nt = 0; nt < 8; nt++) acc[mi][nt] = (f32x4){0.f, 0.f, 0.f, 0.f};
    for (int ks = 0; ks < 6; ks++) {
        bf16x8 a0 = *(const bf16x8*)(A2 + (wave * 16 + rA) * 192 + ks * 32 + qA * 8);
        bf16x8 a1 = *(const bf16x8*)(A2 + ((wave + 4) * 16 + rA) * 192 + ks * 32 + qA * 8);
        #pragma unroll
        for (int nt = 0; nt < 8; nt++) {
            int n = nt * 16 + rA;
            int kb = (ks * 64 + qA * 16) ^ ((n & 7) << 4);
            bf16x8 bhv = *(const bf16x8*)((char*)UTh + n * 384 + kb);
            bf16x8 blv = *(const bf16x8*)((char*)UTl + n * 384 + kb);
            acc[0][nt] = MFMA16(a0, bhv, acc[0][nt]);
            acc[0][nt] = MFMA16(a0, blv, acc[0][nt]);
            acc[1][nt] = MFMA16(a1, bhv, acc[1][nt]);
            acc[1][nt] = MFMA16(a1, blv, acc[1][nt]);
        }
    }
    __syncthreads();   // all UT reads done; yst overlays UTh/UTl

    // ---- epilogue: tanh -> yst[c][l_out], then coalesced store ----
    #pragma unroll
    for (int mi = 0; mi < 2; mi++) {
        int m_base = (wave + mi * 4) * 16 + qA * 4;
        #pragma unroll
        for (int nt = 0; nt < 8; nt++) {
            int c = nt * 16 + rA;
            float4 o;
            o.x = fast_tanh(acc[mi][nt][0]);
            o.y = fast_tanh(acc[mi][nt][1]);
            o.z = fast_tanh(acc[mi][nt][2]);
            o.w = fast_tanh(acc[mi][nt][3]);
            *(float4*)(yst + c * 132 + m_base) = o;
        }
    }
    __syncthreads();
    for (int e = tid; e < 4096; e += 256) {
        int c = e >> 5, l4 = e & 31;
        float4 v = *(const float4*)(yst + c * 132 + l4 * 4);
        *(float4*)(uu + c * 128 + l4 * 4) = v;
    }
}

// ---------------------------------------------------------------------------
// k_linear: in-place channel-mix + tanh (pointwise in l, safe in-place)
// ---------------------------------------------------------------------------
__global__ __launch_bounds__(256)
void k_linear(float* __restrict__ uio, const float* __restrict__ W,
              const float* __restrict__ bias) {
    __shared__ float Wt[64][68];
    __shared__ float Ut[64][64];
    const int b  = blockIdx.y;
    const int l0 = blockIdx.x * 64;
    const int tid = threadIdx.x;

    for (int idx = tid; idx < 4096; idx += 256) {
        int o = idx >> 6, hh = idx & 63;
        Wt[hh][o] = W[idx];
        Ut[o][hh] = uio[(((size_t)(b << 6) | o) << 14) + l0 + hh];
    }
    __syncthreads();

    float acc[4][4];
    #pragma unroll
    for (int j = 0; j < 4; j++)
        #pragma unroll
        for (int k = 0; k < 4; k++) acc[j][k] = 0.f;

    const int og = (tid >> 4) << 2;
    const int lg = (tid & 15) << 2;

    #pragma unroll 4
    for (int hh = 0; hh < 64; ++hh) {
        float4 wv = *(const float4*)&Wt[hh][og];
        float4 uv = *(const float4*)&Ut[hh][lg];
        acc[0][0] = fmaf(wv.x, uv.x, acc[0][0]); acc[0][1] = fmaf(wv.x, uv.y, acc[0][1]);
        acc[0][2] = fmaf(wv.x, uv.z, acc[0][2]); acc[0][3] = fmaf(wv.x, uv.w, acc[0][3]);
        acc[1][0] = fmaf(wv.y, uv.x, acc[1][0]); acc[1][1] = fmaf(wv.y, uv.y, acc[1][1]);
        acc[1][2] = fmaf(wv.y, uv.z, acc[1][2]); acc[1][3] = fmaf(wv.y, uv.w, acc[1][3]);
        acc[2][0] = fmaf(wv.z, uv.x, acc[2][0]); acc[2][1] = fmaf(wv.z, uv.y, acc[2][1]);
        acc[2][2] = fmaf(wv.z, uv.z, acc[2][2]); acc[2][3] = fmaf(wv.z, uv.w, acc[2][3]);
        acc[3][0] = fmaf(wv.w, uv.x, acc[3][0]); acc[3][1] = fmaf(wv.w, uv.y, acc[3][1]);
        acc[3][2] = fmaf(wv.w, uv.z, acc[3][2]); acc[3][3] = fmaf(wv.w, uv.w, acc[3][3]);
    }

    #pragma unroll
    for (int j = 0; j < 4; j++) {
        float bo = bias[og + j];
        float4 o4;
        o4.x = fast_tanh(acc[j][0] + bo);
        o4.y = fast_tanh(acc[j][1] + bo);
        o4.z = fast_tanh(acc[j][2] + bo);
        o4.w = fast_tanh(acc[j][3] + bo);
        *(float4*)&uio[(((size_t)(b << 6) | (og + j)) << 14) + l0 + lg] = o4;
    }
}

// ---------------------------------------------------------------------------
// k_out: out[b,l] = x[b,l] * 10^((sum_h w_out[h]*u[b,h,l] + b_out)/20)
// ---------------------------------------------------------------------------
__global__ __launch_bounds__(256)
void k_out(const float* __restrict__ u, const float* __restrict__ x,
           const float* __restrict__ w_out, const float* __restrict__ b_out,
           float* __restrict__ out) {
    int idx = blockIdx.x * 256 + threadIdx.x;
    int b = idx >> 14;
    int l = idx & (Lq - 1);
    const float* up = u + ((size_t)b << 20) + l;
    float acc = 0.f;
    #pragma unroll 8
    for (int hh = 0; hh < 64; ++hh)
        acc = fmaf(w_out[hh], up[(size_t)hh << 14], acc);
    float g = acc + b_out[0];
    out[idx] = x[idx] * exp2f(g * 0.16609640474436812f);
}

// ---------------------------------------------------------------------------
extern "C" void kernel_launch(void* const* d_in, const int* in_sizes, int n_in,
                              void* d_out, int out_size, void* d_ws, size_t ws_size,
                              hipStream_t stream) {
    const float* x          = (const float*)d_in[0];
    const float* w_in       = (const float*)d_in[1];
    const float* b_in       = (const float*)d_in[2];
    const float* w_mid      = (const float*)d_in[3];
    const float* b_mid      = (const float*)d_in[4];
    const float* w_out      = (const float*)d_in[5];
    const float* b_out      = (const float*)d_in[6];
    const float* log_dt     = (const float*)d_in[7];
    const float* log_A_real = (const float*)d_in[8];
    const float* A_imag     = (const float*)d_in[9];
    const float* C_re       = (const float*)d_in[10];
    const float* C_im       = (const float*)d_in[11];
    const float* Dv         = (const float*)d_in[12];

    char* ws = (char*)d_ws;
    float*          wT_tab = (float*)(ws + WT_OFF_B);
    unsigned short* Wp     = (unsigned short*)(ws + WP_OFF_B);
    unsigned short* A2     = (unsigned short*)(ws + A2_OFF_B);
    float*          u      = (float*)(ws + U_OFF_B);
    float* out = (float*)d_out;

    hipFuncSetAttribute((const void*)k_scan,
                        hipFuncAttributeMaxDynamicSharedMemorySize, SMEM_SZ);

    k_prep<<<NLAYERSq * Hq, 64, 0, stream>>>(log_dt, log_A_real, A_imag,
                                             C_re, C_im, Dv, wT_tab, Wp, A2);
    k_input<<<(Bq * Hq * Lq) / 256, 256, 0, stream>>>(x, w_in, b_in, u);
    for (int layer = 0; layer < NLAYERSq; layer++) {
        if (layer > 0)
            k_linear<<<dim3(Lq / 64, Bq), 256, 0, stream>>>(
                u, w_mid + (size_t)(layer - 1) * Hq * Hq, b_mid + (size_t)(layer - 1) * Hq);
        k_scan<<<Bq * Hq, 256, SMEM_SZ, stream>>>(u, Wp, A2, wT_tab, layer);
    }
    k_out<<<(Bq * Lq) / 256, 256, 0, stream>>>(u, x, w_out, b_out, out);
}

// Round 5
// 287.209 us; speedup vs baseline: 1.5702x; 1.1409x over previous
//
#include <hip/hip_runtime.h>
#include <math.h>

#define Bq 8
#define Lq 16384
#define Hq 64
#define N2q 32
#define NLAYERSq 5

typedef short  bf16x8 __attribute__((ext_vector_type(8)));
typedef float  f32x4  __attribute__((ext_vector_type(4)));

#define MFMA16(a, b, c) __builtin_amdgcn_mfma_f32_16x16x32_bf16(a, b, c, 0, 0, 0)

// ---- LDS layout for k_scan (dynamic) ----
#define UTH_OFF   0           // ushort [128][192]  48 KB  (bf16-hi of [U | S])
#define UTL_OFF   49152       // ushort [128][192]  48 KB  (bf16-lo)
#define SF_OFF    98304       // float  [64][130]   33.28 KB
#define SUB_OFF   131584      // float  [8][32][2]  2 KB
#define SMEM_SZ   133632
#define YST_OFF   0           // float [128][132] overlays UTh/UTl after GEMM2

// ---- workspace layout (bytes) ----
#define WT_OFF_B   0                       // f32 [320][32][4]
#define WP_OFF_B   163840                  // ushort [320][64][128]
#define A2_OFF_B   (163840 + 5242880)      // ushort [320][128][192]
#define U_OFF_B    (163840 + 5242880 + 15728640)   // f32 [512][16384]

__device__ __forceinline__ unsigned short f2bf(float f) {
    union { float f; unsigned int u; } v; v.f = f;
    unsigned int r = v.u + 0x7FFF + ((v.u >> 16) & 1);
    return (unsigned short)(r >> 16);
}
__device__ __forceinline__ float bf2f(unsigned short h) {
    union { unsigned int u; float f; } v; v.u = ((unsigned int)h) << 16;
    return v.f;
}
__device__ __forceinline__ float fast_tanh(float y) {
    float e = __expf(2.0f * y);
    return 1.0f - 2.0f * __builtin_amdgcn_rcpf(e + 1.0f);
}

// ---------------------------------------------------------------------------
// k_prep (parallelized): per (layer,h) coefficient tables.
//   Powers computed directly: w^j = exp(j*dAr) * cis(j*dAi mod 2pi),
//   f64 phase reduction + f32 trig (error ~1e-7 << bf16 table quantum).
//   Wp [64][128]  : rows kk<32 Re(w^{127-l}), kk>=32 Im(w^{127-l})
//   A2 [128][192] : cols 0..127 Toeplitz K[m-k] (K[0] += D); cols 128..191 E
//   wT_tab [32][4]: (wT.re, wT.im, wT16.re, wT16.im), wT = w^128, wT16 = wT^16
// ---------------------------------------------------------------------------
__global__ __launch_bounds__(256)
void k_prep(const float* __restrict__ log_dt, const float* __restrict__ log_A_real,
            const float* __restrict__ A_imag, const float* __restrict__ C_re,
            const float* __restrict__ C_im, const float* __restrict__ Dvec,
            float* __restrict__ wT_tab, unsigned short* __restrict__ Wp,
            unsigned short* __restrict__ A2) {
    __shared__ float Pr[129][33], Pi[129][33];   // stride 33 -> conflict-free
    __shared__ float cre[32], cim[32], Kv[128];
    __shared__ double sdAr[32], sdAi[32];
    const int ph = blockIdx.x;          // layer*64 + h
    const int tid = threadIdx.x;

    if (tid < 32) {
        int n = tid;
        int pidx = ph * N2q + n;
        double dt  = exp((double)log_dt[ph]);
        double aRe = -exp((double)log_A_real[pidx]);
        double aIm = (double)A_imag[pidx];
        double dAr = aRe * dt, dAi = aIm * dt;
        sdAr[n] = dAr; sdAi[n] = dAi;
        double er  = exp(dAr);
        double wre = er * cos(dAi), wim = er * sin(dAi);
        // c = 2 * C * (exp(dtA)-1)/A
        double Er = wre - 1.0, Ei = wim;
        double inv = 1.0 / (aRe * aRe + aIm * aIm);
        double Fr = (Er * aRe + Ei * aIm) * inv;
        double Fi = (Ei * aRe - Er * aIm) * inv;
        double Cr = (double)C_re[pidx], Ci = (double)C_im[pidx];
        cre[n] = (float)(2.0 * (Cr * Fr - Ci * Fi));
        cim[n] = (float)(2.0 * (Cr * Fi + Ci * Fr));
        // wT = w^128 via 7 squarings; wT16 = wT^16 via 4 more (all f64)
        double qr = wre, qi = wim;
        #pragma unroll
        for (int s = 0; s < 7; s++) {
            double nr = qr * qr - qi * qi;
            qi = 2.0 * qr * qi; qr = nr;
        }
        float wTr = (float)qr, wTi = (float)qi;
        #pragma unroll
        for (int s = 0; s < 4; s++) {
            double nr = qr * qr - qi * qi;
            qi = 2.0 * qr * qi; qr = nr;
        }
        float* wt = wT_tab + ph * 128 + n * 4;
        wt[0] = wTr; wt[1] = wTi; wt[2] = (float)qr; wt[3] = (float)qi;
    }
    __syncthreads();

    // powers P[j][n] = w_n^j, j = 0..128 (4128 independent entries)
    const double TWO_PI  = 6.2831853071795864769;
    const double INV_2PI = 0.15915494309189533577;
    for (int e = tid; e < 129 * 32; e += 256) {
        int j = e >> 5, n = e & 31;
        double phd = (double)j * sdAi[n];
        double r   = fma(-TWO_PI, nearbyint(phd * INV_2PI), phd);  // |r| <= pi
        float  mag = __expf((float)((double)j * sdAr[n]));
        float  rf  = (float)r;
        Pr[j][n] = mag * cosf(rf);
        Pi[j][n] = mag * sinf(rf);
    }
    __syncthreads();

    // K[d] = sum_n Re(c_n * w_n^d)  (+ D at d=0)
    if (tid < 128) {
        int d = tid;
        float s = 0.f;
        #pragma unroll 8
        for (int n = 0; n < 32; n++)
            s += cre[n] * Pr[d][n] - cim[n] * Pi[d][n];
        if (d == 0) s += Dvec[ph];
        Kv[d] = s;
    }
    __syncthreads();

    // Wp
    unsigned short* wpb = Wp + (size_t)ph * 8192;
    for (int e = tid; e < 8192; e += 256) {
        int kk = e >> 7, l = e & 127;
        float v = (kk < 32) ? Pr[127 - l][kk] : Pi[127 - l][kk - 32];
        wpb[e] = f2bf(v);
    }
    // A2
    unsigned short* a2b = A2 + (size_t)ph * 24576;
    for (int e = tid; e < 24576; e += 256) {
        int m = e / 192, k = e - m * 192;
        float v;
        if (k < 128) {
            v = (k <= m) ? Kv[m - k] : 0.f;
        } else {
            int kk = k - 128, n2 = kk & 31;
            float pr = Pr[m + 1][n2], pi2 = Pi[m + 1][n2];
            v = (kk < 32) ? (cre[n2] * pr - cim[n2] * pi2)
                          : -(cre[n2] * pi2 + cim[n2] * pr);
        }
        a2b[e] = f2bf(v);
    }
}

// ---------------------------------------------------------------------------
// k_input: u[b,h,l] = tanh( 20*log10(|x[b,l]|+eps) * w_in[h] + b_in[h] )
// ---------------------------------------------------------------------------
__global__ __launch_bounds__(256)
void k_input(const float* __restrict__ x, const float* __restrict__ w_in,
             const float* __restrict__ b_in, float* __restrict__ u) {
    int idx = blockIdx.x * 256 + threadIdx.x;
    int l  = idx & (Lq - 1);
    int bh = idx >> 14;
    int h  = bh & (Hq - 1);
    int b  = bh >> 6;
    float xv = x[(b << 14) + l];
    float s  = 6.0205999132796239f * __log2f(fabsf(xv) + 1e-5f);
    u[idx] = fast_tanh(fmaf(s, w_in[h], b_in[h]));
}

// ---------------------------------------------------------------------------
// k_scan: MFMA DSSM layer, in-place on u[bh][16384]. One WG (256 thr) per bh.
// ---------------------------------------------------------------------------
__global__ __launch_bounds__(256)
void k_scan(float* __restrict__ u, const unsigned short* __restrict__ Wp_all,
            const unsigned short* __restrict__ A2_all,
            const float* __restrict__ wT_all, int layer) {
    extern __shared__ char smem[];
    unsigned short* UTh = (unsigned short*)(smem + UTH_OFF);
    unsigned short* UTl = (unsigned short*)(smem + UTL_OFF);
    float* Sf  = (float*)(smem + SF_OFF);    // [64][130]
    float* sub = (float*)(smem + SUB_OFF);   // [8][32][2]
    float* yst = (float*)(smem + YST_OFF);   // [128][132] overlay

    const int bh = blockIdx.x;
    const int h  = bh & 63;
    const int tid = threadIdx.x;
    const int lane = tid & 63;
    const int wave = tid >> 6;
    const int ph = layer * 64 + h;
    const unsigned short* Wp = Wp_all + (size_t)ph * 8192;
    const unsigned short* A2 = A2_all + (size_t)ph * 24576;
    const float* wT4 = wT_all + ph * 128;
    float* uu = u + ((size_t)bh << 14);

    const int rA = lane & 15;     // fragment row index
    const int qA = lane >> 4;     // fragment k-group

    // ---- stage u -> UTh/UTl (bf16 hi/lo), XOR-swizzled ----
    for (int it = 0; it < 8; ++it) {
        int flat8 = (it * 256 + tid) * 8;
        int n = flat8 >> 7;        // chunk
        int k = flat8 & 127;       // pos in chunk
        float4 a = *(const float4*)(uu + flat8);
        float4 b = *(const float4*)(uu + flat8 + 4);
        float f[8] = {a.x, a.y, a.z, a.w, b.x, b.y, b.z, b.w};
        bf16x8 hi, lo;
        #pragma unroll
        for (int j = 0; j < 8; j++) {
            unsigned short hb = f2bf(f[j]);
            hi[j] = (short)hb;
            lo[j] = (short)f2bf(f[j] - bf2f(hb));
        }
        int kb = (k * 2) ^ ((n & 7) << 4);
        *(bf16x8*)((char*)UTh + n * 384 + kb) = hi;
        *(bf16x8*)((char*)UTl + n * 384 + kb) = lo;
    }
    __syncthreads();

    // ---- GEMM1: Sf[64][128] = Wp . U  (2-pass: B = Uh + Ul) ----
    {
        f32x4 acc1[8];
        #pragma unroll
        for (int nt = 0; nt < 8; nt++) acc1[nt] = (f32x4){0.f, 0.f, 0.f, 0.f};
        const int mt1 = wave;   // rows 16*wave..16*wave+15
        for (int ks = 0; ks < 4; ks++) {
            bf16x8 af = *(const bf16x8*)(Wp + (mt1 * 16 + rA) * 128 + ks * 32 + qA * 8);
            #pragma unroll
            for (int nt = 0; nt < 8; nt++) {
                int n = nt * 16 + rA;
                int kb = (ks * 64 + qA * 16) ^ ((n & 7) << 4);
                bf16x8 bhv = *(const bf16x8*)((char*)UTh + n * 384 + kb);
                bf16x8 blv = *(const bf16x8*)((char*)UTl + n * 384 + kb);
                acc1[nt] = MFMA16(af, bhv, acc1[nt]);
                acc1[nt] = MFMA16(af, blv, acc1[nt]);
            }
        }
        #pragma unroll
        for (int nt = 0; nt < 8; nt++) {
            int c = nt * 16 + rA;
            #pragma unroll
            for (int r = 0; r < 4; r++)
                Sf[(mt1 * 16 + qA * 4 + r) * 130 + c] = acc1[nt][r];
        }
    }
    __syncthreads();

    // ---- hierarchical cross-chunk scan: Sf (local finals) -> Sf (init states)
    const int  sn = tid & 31;       // mode
    const int  ss = tid >> 5;       // sub-block (16 chunks each)
    const float wTr = wT4[sn * 4 + 0], wTi = wT4[sn * 4 + 1];
    {
        float fr[16], fi[16];
        #pragma unroll
        for (int i = 0; i < 16; i++) {
            fr[i] = Sf[sn * 130 + ss * 16 + i];
            fi[i] = Sf[(sn + 32) * 130 + ss * 16 + i];
        }
        float Fr = 0.f, Fi = 0.f;
        #pragma unroll
        for (int i = 0; i < 16; i++) {
            float nFr = fmaf(wTr, Fr, fmaf(-wTi, Fi, fr[i]));
            Fi = fmaf(wTr, Fi, fmaf(wTi, Fr, fi[i]));
            Fr = nFr;
        }
        sub[(ss * 32 + sn) * 2 + 0] = Fr;
        sub[(ss * 32 + sn) * 2 + 1] = Fi;
    }
    __syncthreads();
    if (tid < 32) {
        float w16r = wT4[tid * 4 + 2], w16i = wT4[tid * 4 + 3];
        float Gr = 0.f, Gi = 0.f;
        for (int s = 0; s < 8; s++) {
            float tr = sub[(s * 32 + tid) * 2 + 0];
            float ti = sub[(s * 32 + tid) * 2 + 1];
            sub[(s * 32 + tid) * 2 + 0] = Gr;
            sub[(s * 32 + tid) * 2 + 1] = Gi;
            float nGr = fmaf(w16r, Gr, fmaf(-w16i, Gi, tr));
            Gi = fmaf(w16r, Gi, fmaf(w16i, Gr, ti));
            Gr = nGr;
        }
    }
    __syncthreads();
    {
        float fr[16], fi[16];
        #pragma unroll
        for (int i = 0; i < 16; i++) {
            fr[i] = Sf[sn * 130 + ss * 16 + i];
            fi[i] = Sf[(sn + 32) * 130 + ss * 16 + i];
        }
        float Fr = sub[(ss * 32 + sn) * 2 + 0];
        float Fi = sub[(ss * 32 + sn) * 2 + 1];
        #pragma unroll
        for (int i = 0; i < 16; i++) {
            Sf[sn * 130 + ss * 16 + i] = Fr;          // T_init[c]
            Sf[(sn + 32) * 130 + ss * 16 + i] = Fi;
            float nFr = fmaf(wTr, Fr, fmaf(-wTi, Fi, fr[i]));
            Fi = fmaf(wTr, Fi, fmaf(wTi, Fr, fi[i]));
            Fr = nFr;
        }
    }
    __syncthreads();

    // ---- convert T_init -> UT S-region (bf16 hi/lo, swizzled) ----
    for (int e = tid; e < 8192; e += 256) {
        int kk = e >> 7, c = e & 127;
        float v = Sf[kk * 130 + c];
        unsigned short hb = f2bf(v);
        unsigned short lb = f2bf(v - bf2f(hb));
        int kb = (256 + kk * 2) ^ ((c & 7) << 4);
        *(unsigned short*)((char*)UTh + c * 384 + kb) = hb;
        *(unsigned short*)((char*)UTl + c * 384 + kb) = lb;
    }
    __syncthreads();

    // ---- GEMM2: Y[128][128] = A2[128][192] . [U; S] ----
    f32x4 acc[2][8];
    #pragma unroll
    for (int mi = 0; mi < 2; mi++)
        #pragma unroll
        for (int nt = 0; nt < 8; nt++) acc[mi][nt] = (f32x4){0.f, 0.f, 0.f, 0.f};
    for (int ks = 0; ks < 6; ks++) {
        bf16x8 a0 = *(const bf16x8*)(A2 + (wave * 16 + rA) * 192 + ks * 32 + qA * 8);
        bf16x8 a1 = *(const bf16x8*)(A2 + ((wave + 4) * 16 + rA) * 192 + ks * 32 + qA * 8);
        #pragma unroll
        for (int nt = 0; nt < 8; nt++) {
            int n = nt * 16 + rA;
            int kb = (ks * 64 + qA * 16) ^ ((n & 7) << 4);
            bf16x8 bhv = *(const bf16x8*)((char*)UTh + n * 384 + kb);
            bf16x8 blv = *(const bf16x8*)((char*)UTl + n * 384 + kb);
            acc[0][nt] = MFMA16(a0, bhv, acc[0][nt]);
            acc[0][nt] = MFMA16(a0, blv, acc[0][nt]);
            acc[1][nt] = MFMA16(a1, bhv, acc[1][nt]);
            acc[1][nt] = MFMA16(a1, blv, acc[1][nt]);
        }
    }
    __syncthreads();   // all UT reads done; yst overlays UTh/UTl

    // ---- epilogue: tanh -> yst[c][l_out], then coalesced store ----
    #pragma unroll
    for (int mi = 0; mi < 2; mi++) {
        int m_base = (wave + mi * 4) * 16 + qA * 4;
        #pragma unroll
        for (int nt = 0; nt < 8; nt++) {
            int c = nt * 16 + rA;
            float4 o;
            o.x = fast_tanh(acc[mi][nt][0]);
            o.y = fast_tanh(acc[mi][nt][1]);
            o.z = fast_tanh(acc[mi][nt][2]);
            o.w = fast_tanh(acc[mi][nt][3]);
            *(float4*)(yst + c * 132 + m_base) = o;
        }
    }
    __syncthreads();
    for (int e = tid; e < 4096; e += 256) {
        int c = e >> 5, l4 = e & 31;
        float4 v = *(const float4*)(yst + c * 132 + l4 * 4);
        *(float4*)(uu + c * 128 + l4 * 4) = v;
    }
}

// ---------------------------------------------------------------------------
// k_linear: in-place channel-mix + tanh (pointwise in l, safe in-place)
// ---------------------------------------------------------------------------
__global__ __launch_bounds__(256)
void k_linear(float* __restrict__ uio, const float* __restrict__ W,
              const float* __restrict__ bias) {
    __shared__ float Wt[64][68];
    __shared__ float Ut[64][64];
    const int b  = blockIdx.y;
    const int l0 = blockIdx.x * 64;
    const int tid = threadIdx.x;

    for (int idx = tid; idx < 4096; idx += 256) {
        int o = idx >> 6, hh = idx & 63;
        Wt[hh][o] = W[idx];
        Ut[o][hh] = uio[(((size_t)(b << 6) | o) << 14) + l0 + hh];
    }
    __syncthreads();

    float acc[4][4];
    #pragma unroll
    for (int j = 0; j < 4; j++)
        #pragma unroll
        for (int k = 0; k < 4; k++) acc[j][k] = 0.f;

    const int og = (tid >> 4) << 2;
    const int lg = (tid & 15) << 2;

    #pragma unroll 4
    for (int hh = 0; hh < 64; ++hh) {
        float4 wv = *(const float4*)&Wt[hh][og];
        float4 uv = *(const float4*)&Ut[hh][lg];
        acc[0][0] = fmaf(wv.x, uv.x, acc[0][0]); acc[0][1] = fmaf(wv.x, uv.y, acc[0][1]);
        acc[0][2] = fmaf(wv.x, uv.z, acc[0][2]); acc[0][3] = fmaf(wv.x, uv.w, acc[0][3]);
        acc[1][0] = fmaf(wv.y, uv.x, acc[1][0]); acc[1][1] = fmaf(wv.y, uv.y, acc[1][1]);
        acc[1][2] = fmaf(wv.y, uv.z, acc[1][2]); acc[1][3] = fmaf(wv.y, uv.w, acc[1][3]);
        acc[2][0] = fmaf(wv.z, uv.x, acc[2][0]); acc[2][1] = fmaf(wv.z, uv.y, acc[2][1]);
        acc[2][2] = fmaf(wv.z, uv.z, acc[2][2]); acc[2][3] = fmaf(wv.z, uv.w, acc[2][3]);
        acc[3][0] = fmaf(wv.w, uv.x, acc[3][0]); acc[3][1] = fmaf(wv.w, uv.y, acc[3][1]);
        acc[3][2] = fmaf(wv.w, uv.z, acc[3][2]); acc[3][3] = fmaf(wv.w, uv.w, acc[3][3]);
    }

    #pragma unroll
    for (int j = 0; j < 4; j++) {
        float bo = bias[og + j];
        float4 o4;
        o4.x = fast_tanh(acc[j][0] + bo);
        o4.y = fast_tanh(acc[j][1] + bo);
        o4.z = fast_tanh(acc[j][2] + bo);
        o4.w = fast_tanh(acc[j][3] + bo);
        *(float4*)&uio[(((size_t)(b << 6) | (og + j)) << 14) + l0 + lg] = o4;
    }
}

// ---------------------------------------------------------------------------
// k_out: out[b,l] = x[b,l] * 10^((sum_h w_out[h]*u[b,h,l] + b_out)/20)
// ---------------------------------------------------------------------------
__global__ __launch_bounds__(256)
void k_out(const float* __restrict__ u, const float* __restrict__ x,
           const float* __restrict__ w_out, const float* __restrict__ b_out,
           float* __restrict__ out) {
    int idx = blockIdx.x * 256 + threadIdx.x;
    int b = idx >> 14;
    int l = idx & (Lq - 1);
    const float* up = u + ((size_t)b << 20) + l;
    float acc = 0.f;
    #pragma unroll 8
    for (int hh = 0; hh < 64; ++hh)
        acc = fmaf(w_out[hh], up[(size_t)hh << 14], acc);
    float g = acc + b_out[0];
    out[idx] = x[idx] * exp2f(g * 0.16609640474436812f);
}

// ---------------------------------------------------------------------------
extern "C" void kernel_launch(void* const* d_in, const int* in_sizes, int n_in,
                              void* d_out, int out_size, void* d_ws, size_t ws_size,
                              hipStream_t stream) {
    const float* x          = (const float*)d_in[0];
    const float* w_in       = (const float*)d_in[1];
    const float* b_in       = (const float*)d_in[2];
    const float* w_mid      = (const float*)d_in[3];
    const float* b_mid      = (const float*)d_in[4];
    const float* w_out      = (const float*)d_in[5];
    const float* b_out      = (const float*)d_in[6];
    const float* log_dt     = (const float*)d_in[7];
    const float* log_A_real = (const float*)d_in[8];
    const float* A_imag     = (const float*)d_in[9];
    const float* C_re       = (const float*)d_in[10];
    const float* C_im       = (const float*)d_in[11];
    const float* Dv         = (const float*)d_in[12];

    char* ws = (char*)d_ws;
    float*          wT_tab = (float*)(ws + WT_OFF_B);
    unsigned short* Wp     = (unsigned short*)(ws + WP_OFF_B);
    unsigned short* A2     = (unsigned short*)(ws + A2_OFF_B);
    float*          u      = (float*)(ws + U_OFF_B);
    float* out = (float*)d_out;

    hipFuncSetAttribute((const void*)k_scan,
                        hipFuncAttributeMaxDynamicSharedMemorySize, SMEM_SZ);

    k_prep<<<NLAYERSq * Hq, 256, 0, stream>>>(log_dt, log_A_real, A_imag,
                                              C_re, C_im, Dv, wT_tab, Wp, A2);
    k_input<<<(Bq * Hq * Lq) / 256, 256, 0, stream>>>(x, w_in, b_in, u);
    for (int layer = 0; layer < NLAYERSq; layer++) {
        if (layer > 0)
            k_linear<<<dim3(Lq / 64, Bq), 256, 0, stream>>>(
                u, w_mid + (size_t)(layer - 1) * Hq * Hq, b_mid + (size_t)(layer - 1) * Hq);
        k_scan<<<Bq * Hq, 256, SMEM_SZ, stream>>>(u, Wp, A2, wT_tab, layer);
    }
    k_out<<<(Bq * Lq) / 256, 256, 0, stream>>>(u, x, w_out, b_out, out);
}

// Round 6
// 266.935 us; speedup vs baseline: 1.6894x; 1.0760x over previous
//
#include <hip/hip_runtime.h>
#include <math.h>

#define Bq 8
#define Lq 16384
#define Hq 64
#define N2q 32
#define NLAYERSq 5

typedef short  bf16x8 __attribute__((ext_vector_type(8)));
typedef float  f32x4  __attribute__((ext_vector_type(4)));

#define MFMA16(a, b, c) __builtin_amdgcn_mfma_f32_16x16x32_bf16(a, b, c, 0, 0, 0)

// ---- LDS layout for k_scan (dynamic) ----
#define UTH_OFF   0           // ushort [128][192]  48 KB  (bf16-hi of [U | S])
#define UTL_OFF   49152       // ushort [128][192]  48 KB  (bf16-lo)
#define SF_OFF    98304       // float  [64][130]   33.28 KB
#define SUB_OFF   131584      // float  [16][32][2] 4 KB
#define SMEM_SZ   135680
#define YST_OFF   0           // float [128][132] overlays UTh/UTl after GEMM2

// ---- workspace layout (bytes) ----
#define WT_OFF_B   0                       // f32 [320][32][4]
#define WP_OFF_B   163840                  // ushort [320][64][128]
#define A2_OFF_B   (163840 + 5242880)      // ushort [320][128][192]
#define U_OFF_B    (163840 + 5242880 + 15728640)   // f32 [512][16384]

__device__ __forceinline__ unsigned short f2bf(float f) {
    union { float f; unsigned int u; } v; v.f = f;
    unsigned int r = v.u + 0x7FFF + ((v.u >> 16) & 1);
    return (unsigned short)(r >> 16);
}
__device__ __forceinline__ float bf2f(unsigned short h) {
    union { unsigned int u; float f; } v; v.u = ((unsigned int)h) << 16;
    return v.f;
}
__device__ __forceinline__ float fast_tanh(float y) {
    float e = __expf(2.0f * y);
    return 1.0f - 2.0f * __builtin_amdgcn_rcpf(e + 1.0f);
}

// ---------------------------------------------------------------------------
// k_prep: per (layer,h) coefficient tables (parallel power evaluation).
//   wT_tab [32][4]: (wT.re, wT.im, w8.re, w8.im), wT = w^128, w8 = wT^8
// ---------------------------------------------------------------------------
__global__ __launch_bounds__(256)
void k_prep(const float* __restrict__ log_dt, const float* __restrict__ log_A_real,
            const float* __restrict__ A_imag, const float* __restrict__ C_re,
            const float* __restrict__ C_im, const float* __restrict__ Dvec,
            float* __restrict__ wT_tab, unsigned short* __restrict__ Wp,
            unsigned short* __restrict__ A2) {
    __shared__ float Pr[129][33], Pi[129][33];   // stride 33 -> conflict-free
    __shared__ float cre[32], cim[32], Kv[128];
    __shared__ double sdAr[32], sdAi[32];
    const int ph = blockIdx.x;          // layer*64 + h
    const int tid = threadIdx.x;

    if (tid < 32) {
        int n = tid;
        int pidx = ph * N2q + n;
        double dt  = exp((double)log_dt[ph]);
        double aRe = -exp((double)log_A_real[pidx]);
        double aIm = (double)A_imag[pidx];
        double dAr = aRe * dt, dAi = aIm * dt;
        sdAr[n] = dAr; sdAi[n] = dAi;
        double er  = exp(dAr);
        double wre = er * cos(dAi), wim = er * sin(dAi);
        // c = 2 * C * (exp(dtA)-1)/A
        double Er = wre - 1.0, Ei = wim;
        double inv = 1.0 / (aRe * aRe + aIm * aIm);
        double Fr = (Er * aRe + Ei * aIm) * inv;
        double Fi = (Ei * aRe - Er * aIm) * inv;
        double Cr = (double)C_re[pidx], Ci = (double)C_im[pidx];
        cre[n] = (float)(2.0 * (Cr * Fr - Ci * Fi));
        cim[n] = (float)(2.0 * (Cr * Fi + Ci * Fr));
        // wT = w^128 via 7 squarings; w8 = wT^8 via 3 more (all f64)
        double qr = wre, qi = wim;
        #pragma unroll
        for (int s = 0; s < 7; s++) {
            double nr = qr * qr - qi * qi;
            qi = 2.0 * qr * qi; qr = nr;
        }
        float wTr = (float)qr, wTi = (float)qi;
        #pragma unroll
        for (int s = 0; s < 3; s++) {
            double nr = qr * qr - qi * qi;
            qi = 2.0 * qr * qi; qr = nr;
        }
        float* wt = wT_tab + ph * 128 + n * 4;
        wt[0] = wTr; wt[1] = wTi; wt[2] = (float)qr; wt[3] = (float)qi;
    }
    __syncthreads();

    // powers P[j][n] = w_n^j, j = 0..128 (4128 independent entries)
    const double TWO_PI  = 6.2831853071795864769;
    const double INV_2PI = 0.15915494309189533577;
    for (int e = tid; e < 129 * 32; e += 256) {
        int j = e >> 5, n = e & 31;
        double phd = (double)j * sdAi[n];
        double r   = fma(-TWO_PI, nearbyint(phd * INV_2PI), phd);  // |r| <= pi
        float  mag = __expf((float)((double)j * sdAr[n]));
        float  rf  = (float)r;
        Pr[j][n] = mag * cosf(rf);
        Pi[j][n] = mag * sinf(rf);
    }
    __syncthreads();

    // K[d] = sum_n Re(c_n * w_n^d)  (+ D at d=0)
    if (tid < 128) {
        int d = tid;
        float s = 0.f;
        #pragma unroll 8
        for (int n = 0; n < 32; n++)
            s += cre[n] * Pr[d][n] - cim[n] * Pi[d][n];
        if (d == 0) s += Dvec[ph];
        Kv[d] = s;
    }
    __syncthreads();

    // Wp
    unsigned short* wpb = Wp + (size_t)ph * 8192;
    for (int e = tid; e < 8192; e += 256) {
        int kk = e >> 7, l = e & 127;
        float v = (kk < 32) ? Pr[127 - l][kk] : Pi[127 - l][kk - 32];
        wpb[e] = f2bf(v);
    }
    // A2
    unsigned short* a2b = A2 + (size_t)ph * 24576;
    for (int e = tid; e < 24576; e += 256) {
        int m = e / 192, k = e - m * 192;
        float v;
        if (k < 128) {
            v = (k <= m) ? Kv[m - k] : 0.f;
        } else {
            int kk = k - 128, n2 = kk & 31;
            float pr = Pr[m + 1][n2], pi2 = Pi[m + 1][n2];
            v = (kk < 32) ? (cre[n2] * pr - cim[n2] * pi2)
                          : -(cre[n2] * pi2 + cim[n2] * pr);
        }
        a2b[e] = f2bf(v);
    }
}

// ---------------------------------------------------------------------------
// k_input: u[b,h,l] = tanh( 20*log10(|x[b,l]|+eps) * w_in[h] + b_in[h] )
// ---------------------------------------------------------------------------
__global__ __launch_bounds__(256)
void k_input(const float* __restrict__ x, const float* __restrict__ w_in,
             const float* __restrict__ b_in, float* __restrict__ u) {
    int idx = blockIdx.x * 256 + threadIdx.x;
    int l  = idx & (Lq - 1);
    int bh = idx >> 14;
    int h  = bh & (Hq - 1);
    int b  = bh >> 6;
    float xv = x[(b << 14) + l];
    float s  = 6.0205999132796239f * __log2f(fabsf(xv) + 1e-5f);
    u[idx] = fast_tanh(fmaf(s, w_in[h], b_in[h]));
}

// ---------------------------------------------------------------------------
// k_scan: MFMA DSSM layer, in-place on u[bh][16384]. One WG (512 thr, 8 waves)
// per bh; 2 waves/SIMD for latency hiding.
// ---------------------------------------------------------------------------
__global__ __launch_bounds__(512)
void k_scan(float* __restrict__ u, const unsigned short* __restrict__ Wp_all,
            const unsigned short* __restrict__ A2_all,
            const float* __restrict__ wT_all, int layer) {
    extern __shared__ char smem[];
    unsigned short* UTh = (unsigned short*)(smem + UTH_OFF);
    unsigned short* UTl = (unsigned short*)(smem + UTL_OFF);
    float* Sf  = (float*)(smem + SF_OFF);    // [64][130]
    float* sub = (float*)(smem + SUB_OFF);   // [16][32][2]
    float* yst = (float*)(smem + YST_OFF);   // [128][132] overlay

    const int bh = blockIdx.x;
    const int h  = bh & 63;
    const int tid = threadIdx.x;
    const int lane = tid & 63;
    const int wave = tid >> 6;               // 0..7
    const int ph = layer * 64 + h;
    const unsigned short* Wp = Wp_all + (size_t)ph * 8192;
    const unsigned short* A2 = A2_all + (size_t)ph * 24576;
    const float* wT4 = wT_all + ph * 128;
    float* uu = u + ((size_t)bh << 14);

    const int rA = lane & 15;     // fragment row index
    const int qA = lane >> 4;     // fragment k-group

    // ---- stage u -> UTh/UTl (bf16 hi/lo), XOR-swizzled ----
    for (int it = 0; it < 4; ++it) {
        int flat8 = (it * 512 + tid) * 8;
        int n = flat8 >> 7;        // chunk
        int k = flat8 & 127;       // pos in chunk
        float4 a = *(const float4*)(uu + flat8);
        float4 b = *(const float4*)(uu + flat8 + 4);
        float f[8] = {a.x, a.y, a.z, a.w, b.x, b.y, b.z, b.w};
        bf16x8 hi, lo;
        #pragma unroll
        for (int j = 0; j < 8; j++) {
            unsigned short hb = f2bf(f[j]);
            hi[j] = (short)hb;
            lo[j] = (short)f2bf(f[j] - bf2f(hb));
        }
        int kb = (k * 2) ^ ((n & 7) << 4);
        *(bf16x8*)((char*)UTh + n * 384 + kb) = hi;
        *(bf16x8*)((char*)UTl + n * 384 + kb) = lo;
    }
    __syncthreads();

    // ---- GEMM1: Sf[64][128] = Wp . U  (8 waves: 4 m-tiles x 2 nt-halves) ----
    {
        f32x4 acc1[4];
        #pragma unroll
        for (int nt = 0; nt < 4; nt++) acc1[nt] = (f32x4){0.f, 0.f, 0.f, 0.f};
        const int mt1 = wave & 3;
        const int nh  = (wave >> 2) * 4;     // nt-half base
        for (int ks = 0; ks < 4; ks++) {
            bf16x8 af = *(const bf16x8*)(Wp + (mt1 * 16 + rA) * 128 + ks * 32 + qA * 8);
            #pragma unroll
            for (int nt = 0; nt < 4; nt++) {
                int n = (nh + nt) * 16 + rA;
                int kb = (ks * 64 + qA * 16) ^ ((n & 7) << 4);
                bf16x8 bhv = *(const bf16x8*)((char*)UTh + n * 384 + kb);
                bf16x8 blv = *(const bf16x8*)((char*)UTl + n * 384 + kb);
                acc1[nt] = MFMA16(af, bhv, acc1[nt]);
                acc1[nt] = MFMA16(af, blv, acc1[nt]);
            }
        }
        #pragma unroll
        for (int nt = 0; nt < 4; nt++) {
            int c = (nh + nt) * 16 + rA;
            #pragma unroll
            for (int r = 0; r < 4; r++)
                Sf[(mt1 * 16 + qA * 4 + r) * 130 + c] = acc1[nt][r];
        }
    }
    __syncthreads();

    // ---- hierarchical cross-chunk scan: Sf (local finals) -> Sf (init states)
    const int  sn = tid & 31;       // mode
    const int  ss = tid >> 5;       // sub-block (8 chunks each), 0..15
    const float wTr = wT4[sn * 4 + 0], wTi = wT4[sn * 4 + 1];
    {
        float Fr = 0.f, Fi = 0.f;
        #pragma unroll
        for (int i = 0; i < 8; i++) {
            float fr = Sf[sn * 130 + ss * 8 + i];
            float fi = Sf[(sn + 32) * 130 + ss * 8 + i];
            float nFr = fmaf(wTr, Fr, fmaf(-wTi, Fi, fr));
            Fi = fmaf(wTr, Fi, fmaf(wTi, Fr, fi));
            Fr = nFr;
        }
        sub[(ss * 32 + sn) * 2 + 0] = Fr;
        sub[(ss * 32 + sn) * 2 + 1] = Fi;
    }
    __syncthreads();
    if (tid < 32) {
        float w8r = wT4[tid * 4 + 2], w8i = wT4[tid * 4 + 3];
        float Gr = 0.f, Gi = 0.f;
        for (int s = 0; s < 16; s++) {
            float tr = sub[(s * 32 + tid) * 2 + 0];
            float ti = sub[(s * 32 + tid) * 2 + 1];
            sub[(s * 32 + tid) * 2 + 0] = Gr;
            sub[(s * 32 + tid) * 2 + 1] = Gi;
            float nGr = fmaf(w8r, Gr, fmaf(-w8i, Gi, tr));
            Gi = fmaf(w8r, Gi, fmaf(w8i, Gr, ti));
            Gr = nGr;
        }
    }
    __syncthreads();
    {
        float Fr = sub[(ss * 32 + sn) * 2 + 0];
        float Fi = sub[(ss * 32 + sn) * 2 + 1];
        #pragma unroll
        for (int i = 0; i < 8; i++) {
            float fr = Sf[sn * 130 + ss * 8 + i];
            float fi = Sf[(sn + 32) * 130 + ss * 8 + i];
            Sf[sn * 130 + ss * 8 + i] = Fr;          // T_init[c]
            Sf[(sn + 32) * 130 + ss * 8 + i] = Fi;
            float nFr = fmaf(wTr, Fr, fmaf(-wTi, Fi, fr));
            Fi = fmaf(wTr, Fi, fmaf(wTi, Fr, fi));
            Fr = nFr;
        }
    }
    __syncthreads();

    // ---- convert T_init -> UT S-region (bf16 hi/lo, swizzled) ----
    for (int e = tid; e < 8192; e += 512) {
        int kk = e >> 7, c = e & 127;
        float v = Sf[kk * 130 + c];
        unsigned short hb = f2bf(v);
        unsigned short lb = f2bf(v - bf2f(hb));
        int kb = (256 + kk * 2) ^ ((c & 7) << 4);
        *(unsigned short*)((char*)UTh + c * 384 + kb) = hb;
        *(unsigned short*)((char*)UTl + c * 384 + kb) = lb;
    }
    __syncthreads();

    // ---- GEMM2: Y[128][128] = A2[128][192] . [U; S]  (1 m-tile per wave) ----
    f32x4 acc[8];
    #pragma unroll
    for (int nt = 0; nt < 8; nt++) acc[nt] = (f32x4){0.f, 0.f, 0.f, 0.f};
    for (int ks = 0; ks < 6; ks++) {
        bf16x8 a0 = *(const bf16x8*)(A2 + (wave * 16 + rA) * 192 + ks * 32 + qA * 8);
        #pragma unroll
        for (int nt = 0; nt < 8; nt++) {
            int n = nt * 16 + rA;
            int kb = (ks * 64 + qA * 16) ^ ((n & 7) << 4);
            bf16x8 bhv = *(const bf16x8*)((char*)UTh + n * 384 + kb);
            bf16x8 blv = *(const bf16x8*)((char*)UTl + n * 384 + kb);
            acc[nt] = MFMA16(a0, bhv, acc[nt]);
            acc[nt] = MFMA16(a0, blv, acc[nt]);
        }
    }
    __syncthreads();   // all UT reads done; yst overlays UTh/UTl

    // ---- epilogue: tanh -> yst[c][l_out], then coalesced store ----
    {
        int m_base = wave * 16 + qA * 4;
        #pragma unroll
        for (int nt = 0; nt < 8; nt++) {
            int c = nt * 16 + rA;
            float4 o;
            o.x = fast_tanh(acc[nt][0]);
            o.y = fast_tanh(acc[nt][1]);
            o.z = fast_tanh(acc[nt][2]);
            o.w = fast_tanh(acc[nt][3]);
            *(float4*)(yst + c * 132 + m_base) = o;
        }
    }
    __syncthreads();
    for (int e = tid; e < 4096; e += 512) {
        int c = e >> 5, l4 = e & 31;
        float4 v = *(const float4*)(yst + c * 132 + l4 * 4);
        *(float4*)(uu + c * 128 + l4 * 4) = v;
    }
}

// ---------------------------------------------------------------------------
// k_linear: in-place channel-mix + tanh (pointwise in l, safe in-place)
// ---------------------------------------------------------------------------
__global__ __launch_bounds__(256)
void k_linear(float* __restrict__ uio, const float* __restrict__ W,
              const float* __restrict__ bias) {
    __shared__ float Wt[64][68];
    __shared__ float Ut[64][64];
    const int b  = blockIdx.y;
    const int l0 = blockIdx.x * 64;
    const int tid = threadIdx.x;

    for (int idx = tid; idx < 4096; idx += 256) {
        int o = idx >> 6, hh = idx & 63;
        Wt[hh][o] = W[idx];
        Ut[o][hh] = uio[(((size_t)(b << 6) | o) << 14) + l0 + hh];
    }
    __syncthreads();

    float acc[4][4];
    #pragma unroll
    for (int j = 0; j < 4; j++)
        #pragma unroll
        for (int k = 0; k < 4; k++) acc[j][k] = 0.f;

    const int og = (tid >> 4) << 2;
    const int lg = (tid & 15) << 2;

    #pragma unroll 4
    for (int hh = 0; hh < 64; ++hh) {
        float4 wv = *(const float4*)&Wt[hh][og];
        float4 uv = *(const float4*)&Ut[hh][lg];
        acc[0][0] = fmaf(wv.x, uv.x, acc[0][0]); acc[0][1] = fmaf(wv.x, uv.y, acc[0][1]);
        acc[0][2] = fmaf(wv.x, uv.z, acc[0][2]); acc[0][3] = fmaf(wv.x, uv.w, acc[0][3]);
        acc[1][0] = fmaf(wv.y, uv.x, acc[1][0]); acc[1][1] = fmaf(wv.y, uv.y, acc[1][1]);
        acc[1][2] = fmaf(wv.y, uv.z, acc[1][2]); acc[1][3] = fmaf(wv.y, uv.w, acc[1][3]);
        acc[2][0] = fmaf(wv.z, uv.x, acc[2][0]); acc[2][1] = fmaf(wv.z, uv.y, acc[2][1]);
        acc[2][2] = fmaf(wv.z, uv.z, acc[2][2]); acc[2][3] = fmaf(wv.z, uv.w, acc[2][3]);
        acc[3][0] = fmaf(wv.w, uv.x, acc[3][0]); acc[3][1] = fmaf(wv.w, uv.y, acc[3][1]);
        acc[3][2] = fmaf(wv.w, uv.z, acc[3][2]); acc[3][3] = fmaf(wv.w, uv.w, acc[3][3]);
    }

    #pragma unroll
    for (int j = 0; j < 4; j++) {
        float bo = bias[og + j];
        float4 o4;
        o4.x = fast_tanh(acc[j][0] + bo);
        o4.y = fast_tanh(acc[j][1] + bo);
        o4.z = fast_tanh(acc[j][2] + bo);
        o4.w = fast_tanh(acc[j][3] + bo);
        *(float4*)&uio[(((size_t)(b << 6) | (og + j)) << 14) + l0 + lg] = o4;
    }
}

// ---------------------------------------------------------------------------
// k_out: out[b,l] = x[b,l] * 10^((sum_h w_out[h]*u[b,h,l] + b_out)/20)
// ---------------------------------------------------------------------------
__global__ __launch_bounds__(256)
void k_out(const float* __restrict__ u, const float* __restrict__ x,
           const float* __restrict__ w_out, const float* __restrict__ b_out,
           float* __restrict__ out) {
    int idx = blockIdx.x * 256 + threadIdx.x;
    int b = idx >> 14;
    int l = idx & (Lq - 1);
    const float* up = u + ((size_t)b << 20) + l;
    float acc = 0.f;
    #pragma unroll 8
    for (int hh = 0; hh < 64; ++hh)
        acc = fmaf(w_out[hh], up[(size_t)hh << 14], acc);
    float g = acc + b_out[0];
    out[idx] = x[idx] * exp2f(g * 0.16609640474436812f);
}

// ---------------------------------------------------------------------------
extern "C" void kernel_launch(void* const* d_in, const int* in_sizes, int n_in,
                              void* d_out, int out_size, void* d_ws, size_t ws_size,
                              hipStream_t stream) {
    const float* x          = (const float*)d_in[0];
    const float* w_in       = (const float*)d_in[1];
    const float* b_in       = (const float*)d_in[2];
    const float* w_mid      = (const float*)d_in[3];
    const float* b_mid      = (const float*)d_in[4];
    const float* w_out      = (const float*)d_in[5];
    const float* b_out      = (const float*)d_in[6];
    const float* log_dt     = (const float*)d_in[7];
    const float* log_A_real = (const float*)d_in[8];
    const float* A_imag     = (const float*)d_in[9];
    const float* C_re       = (const float*)d_in[10];
    const float* C_im       = (const float*)d_in[11];
    const float* Dv         = (const float*)d_in[12];

    char* ws = (char*)d_ws;
    float*          wT_tab = (float*)(ws + WT_OFF_B);
    unsigned short* Wp     = (unsigned short*)(ws + WP_OFF_B);
    unsigned short* A2     = (unsigned short*)(ws + A2_OFF_B);
    float*          u      = (float*)(ws + U_OFF_B);
    float* out = (float*)d_out;

    hipFuncSetAttribute((const void*)k_scan,
                        hipFuncAttributeMaxDynamicSharedMemorySize, SMEM_SZ);

    k_prep<<<NLAYERSq * Hq, 256, 0, stream>>>(log_dt, log_A_real, A_imag,
                                              C_re, C_im, Dv, wT_tab, Wp, A2);
    k_input<<<(Bq * Hq * Lq) / 256, 256, 0, stream>>>(x, w_in, b_in, u);
    for (int layer = 0; layer < NLAYERSq; layer++) {
        if (layer > 0)
            k_linear<<<dim3(Lq / 64, Bq), 256, 0, stream>>>(
                u, w_mid + (size_t)(layer - 1) * Hq * Hq, b_mid + (size_t)(layer - 1) * Hq);
        k_scan<<<Bq * Hq, 512, SMEM_SZ, stream>>>(u, Wp, A2, wT_tab, layer);
    }
    k_out<<<(Bq * Lq) / 256, 256, 0, stream>>>(u, x, w_out, b_out, out);
}

// Round 7
// 226.351 us; speedup vs baseline: 1.9923x; 1.1793x over previous
//
#include <hip/hip_runtime.h>
#include <math.h>

#define Bq 8
#define Lq 16384
#define Hq 64
#define N2q 32
#define NLAYERSq 5

typedef _Float16 f16x8 __attribute__((ext_vector_type(8)));
typedef float    f32x4 __attribute__((ext_vector_type(4)));

#define MFMA16F(a, b, c) __builtin_amdgcn_mfma_f32_16x16x32_f16(a, b, c, 0, 0, 0)

// ---- LDS layout for k_scan (dynamic): exactly 80 KB -> 2 WG/CU ----
#define UT_OFF    0           // _Float16 [128][192]  48 KB  ([U | S])
#define SF_OFF    49152       // float    [64][128]   32 KB  (XOR-swizzled)
#define SMEM_SZ   81920
#define YST_OFF   0           // float [128][132] overlays UT+Sf after GEMM2
// Sf addressing: bank-conflict-free via column XOR swizzle
#define SF(row, c) ((row) * 128 + ((c) ^ ((row) & 31)))

// ---- workspace layout (bytes) ----
#define WT_OFF_B   0                       // f32 [320][32][4]
#define WP_OFF_B   163840                  // f16 [320][64][128]
#define A2_OFF_B   (163840 + 5242880)      // f16 [320][128][192]
#define U_OFF_B    (163840 + 5242880 + 15728640)   // f32 [512][16384]

__device__ __forceinline__ float fast_tanh(float y) {
    float e = __expf(2.0f * y);
    return 1.0f - 2.0f * __builtin_amdgcn_rcpf(e + 1.0f);
}

// ---------------------------------------------------------------------------
// k_prep: per (layer,h) coefficient tables (fp16), parallel power evaluation.
//   Wp [64][128]  : rows kk<32 Re(w^{127-l}), kk>=32 Im(w^{127-l})
//   A2 [128][192] : cols 0..127 Toeplitz K[m-k] (K[0]+=D); cols 128..191 E
//   wT_tab [32][4]: (wT.re, wT.im, w8.re, w8.im), wT = w^128, w8 = wT^8
// ---------------------------------------------------------------------------
__global__ __launch_bounds__(256)
void k_prep(const float* __restrict__ log_dt, const float* __restrict__ log_A_real,
            const float* __restrict__ A_imag, const float* __restrict__ C_re,
            const float* __restrict__ C_im, const float* __restrict__ Dvec,
            float* __restrict__ wT_tab, _Float16* __restrict__ Wp,
            _Float16* __restrict__ A2) {
    __shared__ float Pr[129][33], Pi[129][33];   // stride 33 -> conflict-free
    __shared__ float cre[32], cim[32], Kv[128];
    __shared__ double sdAr[32], sdAi[32];
    const int ph = blockIdx.x;          // layer*64 + h
    const int tid = threadIdx.x;

    if (tid < 32) {
        int n = tid;
        int pidx = ph * N2q + n;
        double dt  = exp((double)log_dt[ph]);
        double aRe = -exp((double)log_A_real[pidx]);
        double aIm = (double)A_imag[pidx];
        double dAr = aRe * dt, dAi = aIm * dt;
        sdAr[n] = dAr; sdAi[n] = dAi;
        double er  = exp(dAr);
        double wre = er * cos(dAi), wim = er * sin(dAi);
        double Er = wre - 1.0, Ei = wim;
        double inv = 1.0 / (aRe * aRe + aIm * aIm);
        double Fr = (Er * aRe + Ei * aIm) * inv;
        double Fi = (Ei * aRe - Er * aIm) * inv;
        double Cr = (double)C_re[pidx], Ci = (double)C_im[pidx];
        cre[n] = (float)(2.0 * (Cr * Fr - Ci * Fi));
        cim[n] = (float)(2.0 * (Cr * Fi + Ci * Fr));
        // wT = w^128 via 7 squarings; w8 = wT^8 via 3 more (all f64)
        double qr = wre, qi = wim;
        #pragma unroll
        for (int s = 0; s < 7; s++) {
            double nr = qr * qr - qi * qi;
            qi = 2.0 * qr * qi; qr = nr;
        }
        float wTr = (float)qr, wTi = (float)qi;
        #pragma unroll
        for (int s = 0; s < 3; s++) {
            double nr = qr * qr - qi * qi;
            qi = 2.0 * qr * qi; qr = nr;
        }
        float* wt = wT_tab + ph * 128 + n * 4;
        wt[0] = wTr; wt[1] = wTi; wt[2] = (float)qr; wt[3] = (float)qi;
    }
    __syncthreads();

    const double TWO_PI  = 6.2831853071795864769;
    const double INV_2PI = 0.15915494309189533577;
    for (int e = tid; e < 129 * 32; e += 256) {
        int j = e >> 5, n = e & 31;
        double phd = (double)j * sdAi[n];
        double r   = fma(-TWO_PI, nearbyint(phd * INV_2PI), phd);  // |r| <= pi
        float  mag = __expf((float)((double)j * sdAr[n]));
        float  rf  = (float)r;
        Pr[j][n] = mag * cosf(rf);
        Pi[j][n] = mag * sinf(rf);
    }
    __syncthreads();

    if (tid < 128) {
        int d = tid;
        float s = 0.f;
        #pragma unroll 8
        for (int n = 0; n < 32; n++)
            s += cre[n] * Pr[d][n] - cim[n] * Pi[d][n];
        if (d == 0) s += Dvec[ph];
        Kv[d] = s;
    }
    __syncthreads();

    _Float16* wpb = Wp + (size_t)ph * 8192;
    for (int e = tid; e < 8192; e += 256) {
        int kk = e >> 7, l = e & 127;
        float v = (kk < 32) ? Pr[127 - l][kk] : Pi[127 - l][kk - 32];
        wpb[e] = (_Float16)v;
    }
    _Float16* a2b = A2 + (size_t)ph * 24576;
    for (int e = tid; e < 24576; e += 256) {
        int m = e / 192, k = e - m * 192;
        float v;
        if (k < 128) {
            v = (k <= m) ? Kv[m - k] : 0.f;
        } else {
            int kk = k - 128, n2 = kk & 31;
            float pr = Pr[m + 1][n2], pi2 = Pi[m + 1][n2];
            v = (kk < 32) ? (cre[n2] * pr - cim[n2] * pi2)
                          : -(cre[n2] * pi2 + cim[n2] * pr);
        }
        a2b[e] = (_Float16)v;
    }
}

// ---------------------------------------------------------------------------
// k_input: u[b,h,l] = tanh( 20*log10(|x[b,l]|+eps) * w_in[h] + b_in[h] )
// ---------------------------------------------------------------------------
__global__ __launch_bounds__(256)
void k_input(const float* __restrict__ x, const float* __restrict__ w_in,
             const float* __restrict__ b_in, float* __restrict__ u) {
    int idx = blockIdx.x * 256 + threadIdx.x;
    int l  = idx & (Lq - 1);
    int bh = idx >> 14;
    int h  = bh & (Hq - 1);
    int b  = bh >> 6;
    float xv = x[(b << 14) + l];
    float s  = 6.0205999132796239f * __log2f(fabsf(xv) + 1e-5f);
    u[idx] = fast_tanh(fmaf(s, w_in[h], b_in[h]));
}

// ---------------------------------------------------------------------------
// k_scan: fp16 MFMA DSSM layer, in-place on u[bh][16384]. One WG (512 thr,
// 8 waves) per bh; 80 KB LDS -> 2 WG/CU, all 512 blocks co-resident.
// ---------------------------------------------------------------------------
__global__ __launch_bounds__(512, 4)
void k_scan(float* __restrict__ u, const _Float16* __restrict__ Wp_all,
            const _Float16* __restrict__ A2_all,
            const float* __restrict__ wT_all, int layer) {
    extern __shared__ char smem[];
    _Float16* UT = (_Float16*)(smem + UT_OFF);   // [128][192]
    float*    Sf = (float*)(smem + SF_OFF);      // [64][128] swizzled
    float*   yst = (float*)(smem + YST_OFF);     // [128][132] overlay

    const int bh = blockIdx.x;
    const int h  = bh & 63;
    const int tid = threadIdx.x;
    const int lane = tid & 63;
    const int wave = tid >> 6;               // 0..7
    const int ph = layer * 64 + h;
    const _Float16* Wp = Wp_all + (size_t)ph * 8192;
    const _Float16* A2 = A2_all + (size_t)ph * 24576;
    const float* wT4 = wT_all + ph * 128;
    float* uu = u + ((size_t)bh << 14);

    const int rA = lane & 15;     // fragment row/col index
    const int qA = lane >> 4;     // fragment k-group

    // ---- stage u -> UT (fp16), XOR-swizzled ----
    for (int it = 0; it < 4; ++it) {
        int flat8 = (it * 512 + tid) * 8;
        int n = flat8 >> 7;        // chunk
        int k = flat8 & 127;       // pos in chunk
        float4 a = *(const float4*)(uu + flat8);
        float4 b = *(const float4*)(uu + flat8 + 4);
        float f[8] = {a.x, a.y, a.z, a.w, b.x, b.y, b.z, b.w};
        f16x8 hv;
        #pragma unroll
        for (int j = 0; j < 8; j++) hv[j] = (_Float16)f[j];
        int kb = (k * 2) ^ ((n & 7) << 4);
        *(f16x8*)((char*)UT + n * 384 + kb) = hv;
    }
    __syncthreads();

    // ---- GEMM1: Sf[64][128] = Wp . U  (8 waves: 4 m-tiles x 2 nt-halves) ----
    {
        f32x4 acc1[4];
        #pragma unroll
        for (int nt = 0; nt < 4; nt++) acc1[nt] = (f32x4){0.f, 0.f, 0.f, 0.f};
        const int mt1 = wave & 3;
        const int nh  = (wave >> 2) * 4;     // nt-half base
        for (int ks = 0; ks < 4; ks++) {
            f16x8 af = *(const f16x8*)(Wp + (mt1 * 16 + rA) * 128 + ks * 32 + qA * 8);
            #pragma unroll
            for (int nt = 0; nt < 4; nt++) {
                int n = (nh + nt) * 16 + rA;
                int kb = (ks * 64 + qA * 16) ^ ((n & 7) << 4);
                f16x8 bv = *(const f16x8*)((char*)UT + n * 384 + kb);
                acc1[nt] = MFMA16F(af, bv, acc1[nt]);
            }
        }
        #pragma unroll
        for (int nt = 0; nt < 4; nt++) {
            int c = (nh + nt) * 16 + rA;
            #pragma unroll
            for (int r = 0; r < 4; r++)
                Sf[SF(mt1 * 16 + qA * 4 + r, c)] = acc1[nt][r];
        }
    }
    __syncthreads();

    // ---- cross-chunk scan, register-resident (no extra barriers) ----
    // lane (sn, ss): sn = mode 0..31, ss = sub-block 0..15 (8 chunks each)
    {
        const int sn = tid >> 4;
        const int ss = tid & 15;
        const float wTr = wT4[sn * 4 + 0], wTi = wT4[sn * 4 + 1];
        float fr[8], fi[8];
        #pragma unroll
        for (int i = 0; i < 8; i++) {
            fr[i] = Sf[SF(sn,      ss * 8 + i)];
            fi[i] = Sf[SF(sn + 32, ss * 8 + i)];
        }
        // sub-block total
        float Tr = 0.f, Ti = 0.f;
        #pragma unroll
        for (int i = 0; i < 8; i++) {
            float nTr = fmaf(wTr, Tr, fmaf(-wTi, Ti, fr[i]));
            Ti = fmaf(wTr, Ti, fmaf(wTi, Tr, fi[i]));
            Tr = nTr;
        }
        // Kogge-Stone inclusive scan over ss (width 16), decay wT^(8*2^s)
        float gr = wT4[sn * 4 + 2], gi = wT4[sn * 4 + 3];   // wT^8
        #pragma unroll
        for (int s = 0; s < 4; s++) {
            float pr = __shfl_up(Tr, 1 << s, 16);
            float pi = __shfl_up(Ti, 1 << s, 16);
            if (ss >= (1 << s)) {
                Tr = fmaf(gr, pr, fmaf(-gi, pi, Tr));
                Ti = fmaf(gr, pi, fmaf(gi, pr, Ti));
            }
            float ngr = fmaf(gr, gr, -gi * gi);
            gi = 2.f * gr * gi; gr = ngr;
        }
        // exclusive: state before sub-block ss
        float Er_ = __shfl_up(Tr, 1, 16);
        float Ei_ = __shfl_up(Ti, 1, 16);
        if (ss == 0) { Er_ = 0.f; Ei_ = 0.f; }
        // replay: write per-chunk init states
        float Gr = Er_, Gi = Ei_;
        #pragma unroll
        for (int i = 0; i < 8; i++) {
            Sf[SF(sn,      ss * 8 + i)] = Gr;
            Sf[SF(sn + 32, ss * 8 + i)] = Gi;
            float nGr = fmaf(wTr, Gr, fmaf(-wTi, Gi, fr[i]));
            Gi = fmaf(wTr, Gi, fmaf(wTi, Gr, fi[i]));
            Gr = nGr;
        }
    }
    __syncthreads();

    // ---- convert T_init -> UT S-region (fp16, swizzled) ----
    for (int e = tid; e < 8192; e += 512) {
        int kk = e >> 7, c = e & 127;
        float v = Sf[SF(kk, c)];
        int kb = (256 + kk * 2) ^ ((c & 7) << 4);
        *(_Float16*)((char*)UT + c * 384 + kb) = (_Float16)v;
    }
    __syncthreads();

    // ---- GEMM2: Y[128][128] = A2[128][192] . [U; S]  (1 m-tile per wave) ----
    f32x4 acc[8];
    #pragma unroll
    for (int nt = 0; nt < 8; nt++) acc[nt] = (f32x4){0.f, 0.f, 0.f, 0.f};
    for (int ks = 0; ks < 6; ks++) {
        f16x8 a0 = *(const f16x8*)(A2 + (wave * 16 + rA) * 192 + ks * 32 + qA * 8);
        #pragma unroll
        for (int nt = 0; nt < 8; nt++) {
            int n = nt * 16 + rA;
            int kb = (ks * 64 + qA * 16) ^ ((n & 7) << 4);
            f16x8 bv = *(const f16x8*)((char*)UT + n * 384 + kb);
            acc[nt] = MFMA16F(a0, bv, acc[nt]);
        }
    }
    __syncthreads();   // all UT/Sf reads done; yst overlays them

    // ---- epilogue: tanh -> yst[c][l_out], then coalesced store ----
    {
        int m_base = wave * 16 + qA * 4;
        #pragma unroll
        for (int nt = 0; nt < 8; nt++) {
            int c = nt * 16 + rA;
            float4 o;
            o.x = fast_tanh(acc[nt][0]);
            o.y = fast_tanh(acc[nt][1]);
            o.z = fast_tanh(acc[nt][2]);
            o.w = fast_tanh(acc[nt][3]);
            *(float4*)(yst + c * 132 + m_base) = o;
        }
    }
    __syncthreads();
    for (int e = tid; e < 4096; e += 512) {
        int c = e >> 5, l4 = e & 31;
        float4 v = *(const float4*)(yst + c * 132 + l4 * 4);
        *(float4*)(uu + c * 128 + l4 * 4) = v;
    }
}

// ---------------------------------------------------------------------------
// k_linear: in-place channel-mix + tanh (pointwise in l, safe in-place)
// ---------------------------------------------------------------------------
__global__ __launch_bounds__(256)
void k_linear(float* __restrict__ uio, const float* __restrict__ W,
              const float* __restrict__ bias) {
    __shared__ float Wt[64][68];
    __shared__ float Ut[64][64];
    const int b  = blockIdx.y;
    const int l0 = blockIdx.x * 64;
    const int tid = threadIdx.x;

    for (int idx = tid; idx < 4096; idx += 256) {
        int o = idx >> 6, hh = idx & 63;
        Wt[hh][o] = W[idx];
        Ut[o][hh] = uio[(((size_t)(b << 6) | o) << 14) + l0 + hh];
    }
    __syncthreads();

    float acc[4][4];
    #pragma unroll
    for (int j = 0; j < 4; j++)
        #pragma unroll
        for (int k = 0; k < 4; k++) acc[j][k] = 0.f;

    const int og = (tid >> 4) << 2;
    const int lg = (tid & 15) << 2;

    #pragma unroll 4
    for (int hh = 0; hh < 64; ++hh) {
        float4 wv = *(const float4*)&Wt[hh][og];
        float4 uv = *(const float4*)&Ut[hh][lg];
        acc[0][0] = fmaf(wv.x, uv.x, acc[0][0]); acc[0][1] = fmaf(wv.x, uv.y, acc[0][1]);
        acc[0][2] = fmaf(wv.x, uv.z, acc[0][2]); acc[0][3] = fmaf(wv.x, uv.w, acc[0][3]);
        acc[1][0] = fmaf(wv.y, uv.x, acc[1][0]); acc[1][1] = fmaf(wv.y, uv.y, acc[1][1]);
        acc[1][2] = fmaf(wv.y, uv.z, acc[1][2]); acc[1][3] = fmaf(wv.y, uv.w, acc[1][3]);
        acc[2][0] = fmaf(wv.z, uv.x, acc[2][0]); acc[2][1] = fmaf(wv.z, uv.y, acc[2][1]);
        acc[2][2] = fmaf(wv.z, uv.z, acc[2][2]); acc[2][3] = fmaf(wv.z, uv.w, acc[2][3]);
        acc[3][0] = fmaf(wv.w, uv.x, acc[3][0]); acc[3][1] = fmaf(wv.w, uv.y, acc[3][1]);
        acc[3][2] = fmaf(wv.w, uv.z, acc[3][2]); acc[3][3] = fmaf(wv.w, uv.w, acc[3][3]);
    }

    #pragma unroll
    for (int j = 0; j < 4; j++) {
        float bo = bias[og + j];
        float4 o4;
        o4.x = fast_tanh(acc[j][0] + bo);
        o4.y = fast_tanh(acc[j][1] + bo);
        o4.z = fast_tanh(acc[j][2] + bo);
        o4.w = fast_tanh(acc[j][3] + bo);
        *(float4*)&uio[(((size_t)(b << 6) | (og + j)) << 14) + l0 + lg] = o4;
    }
}

// ---------------------------------------------------------------------------
// k_out: out[b,l] = x[b,l] * 10^((sum_h w_out[h]*u[b,h,l] + b_out)/20)
// ---------------------------------------------------------------------------
__global__ __launch_bounds__(256)
void k_out(const float* __restrict__ u, const float* __restrict__ x,
           const float* __restrict__ w_out, const float* __restrict__ b_out,
           float* __restrict__ out) {
    int idx = blockIdx.x * 256 + threadIdx.x;
    int b = idx >> 14;
    int l = idx & (Lq - 1);
    const float* up = u + ((size_t)b << 20) + l;
    float acc = 0.f;
    #pragma unroll 8
    for (int hh = 0; hh < 64; ++hh)
        acc = fmaf(w_out[hh], up[(size_t)hh << 14], acc);
    float g = acc + b_out[0];
    out[idx] = x[idx] * exp2f(g * 0.16609640474436812f);
}

// ---------------------------------------------------------------------------
extern "C" void kernel_launch(void* const* d_in, const int* in_sizes, int n_in,
                              void* d_out, int out_size, void* d_ws, size_t ws_size,
                              hipStream_t stream) {
    const float* x          = (const float*)d_in[0];
    const float* w_in       = (const float*)d_in[1];
    const float* b_in       = (const float*)d_in[2];
    const float* w_mid      = (const float*)d_in[3];
    const float* b_mid      = (const float*)d_in[4];
    const float* w_out      = (const float*)d_in[5];
    const float* b_out      = (const float*)d_in[6];
    const float* log_dt     = (const float*)d_in[7];
    const float* log_A_real = (const float*)d_in[8];
    const float* A_imag     = (const float*)d_in[9];
    const float* C_re       = (const float*)d_in[10];
    const float* C_im       = (const float*)d_in[11];
    const float* Dv         = (const float*)d_in[12];

    char* ws = (char*)d_ws;
    float*     wT_tab = (float*)(ws + WT_OFF_B);
    _Float16*  Wp     = (_Float16*)(ws + WP_OFF_B);
    _Float16*  A2     = (_Float16*)(ws + A2_OFF_B);
    float*     u      = (float*)(ws + U_OFF_B);
    float* out = (float*)d_out;

    hipFuncSetAttribute((const void*)k_scan,
                        hipFuncAttributeMaxDynamicSharedMemorySize, SMEM_SZ);

    k_prep<<<NLAYERSq * Hq, 256, 0, stream>>>(log_dt, log_A_real, A_imag,
                                              C_re, C_im, Dv, wT_tab, Wp, A2);
    k_input<<<(Bq * Hq * Lq) / 256, 256, 0, stream>>>(x, w_in, b_in, u);
    for (int layer = 0; layer < NLAYERSq; layer++) {
        if (layer > 0)
            k_linear<<<dim3(Lq / 64, Bq), 256, 0, stream>>>(
                u, w_mid + (size_t)(layer - 1) * Hq * Hq, b_mid + (size_t)(layer - 1) * Hq);
        k_scan<<<Bq * Hq, 512, SMEM_SZ, stream>>>(u, Wp, A2, wT_tab, layer);
    }
    k_out<<<(Bq * Lq) / 256, 256, 0, stream>>>(u, x, w_out, b_out, out);
}

// Round 8
// 214.824 us; speedup vs baseline: 2.0992x; 1.0537x over previous
//
#include <hip/hip_runtime.h>
#include <math.h>

#define Bq 8
#define Lq 16384
#define Hq 64
#define N2q 32
#define NLAYERSq 5

typedef _Float16 f16x8 __attribute__((ext_vector_type(8)));
typedef _Float16 f16x4 __attribute__((ext_vector_type(4)));
typedef float    f32x4 __attribute__((ext_vector_type(4)));

#define MFMA16F(a, b, c) __builtin_amdgcn_mfma_f32_16x16x32_f16(a, b, c, 0, 0, 0)

// ---- LDS layout for k_scan (dynamic): exactly 80 KB -> 2 WG/CU ----
#define UT_OFF    0           // _Float16 [128][192]  48 KB  ([U | S])
#define SF_OFF    49152       // float    [64][128]   32 KB  (XOR-swizzled)
#define SMEM_SZ   81920
#define YST_OFF   0           // float [128][132] overlays UT+Sf after GEMM2
#define SF(row, c) ((row) * 128 + ((c) ^ ((row) & 31)))

// ---- workspace layout (bytes) ----
#define WT_OFF_B   0                       // f32 [320][32][4]
#define WP_OFF_B   163840                  // f16 [320][64][128]
#define A2_OFF_B   (163840 + 5242880)      // f16 [320][128][192]
#define U_OFF_B    (163840 + 5242880 + 15728640)   // f16 [512][16384]

__device__ __forceinline__ float fast_tanh(float y) {
    float e = __expf(2.0f * y);
    return 1.0f - 2.0f * __builtin_amdgcn_rcpf(e + 1.0f);
}

// ---------------------------------------------------------------------------
// k_prep: per (layer,h) coefficient tables (fp16), parallel power evaluation.
// ---------------------------------------------------------------------------
__global__ __launch_bounds__(256)
void k_prep(const float* __restrict__ log_dt, const float* __restrict__ log_A_real,
            const float* __restrict__ A_imag, const float* __restrict__ C_re,
            const float* __restrict__ C_im, const float* __restrict__ Dvec,
            float* __restrict__ wT_tab, _Float16* __restrict__ Wp,
            _Float16* __restrict__ A2) {
    __shared__ float Pr[129][33], Pi[129][33];
    __shared__ float cre[32], cim[32], Kv[128];
    __shared__ double sdAr[32], sdAi[32];
    const int ph = blockIdx.x;          // layer*64 + h
    const int tid = threadIdx.x;

    if (tid < 32) {
        int n = tid;
        int pidx = ph * N2q + n;
        double dt  = exp((double)log_dt[ph]);
        double aRe = -exp((double)log_A_real[pidx]);
        double aIm = (double)A_imag[pidx];
        double dAr = aRe * dt, dAi = aIm * dt;
        sdAr[n] = dAr; sdAi[n] = dAi;
        double er  = exp(dAr);
        double wre = er * cos(dAi), wim = er * sin(dAi);
        double Er = wre - 1.0, Ei = wim;
        double inv = 1.0 / (aRe * aRe + aIm * aIm);
        double Fr = (Er * aRe + Ei * aIm) * inv;
        double Fi = (Ei * aRe - Er * aIm) * inv;
        double Cr = (double)C_re[pidx], Ci = (double)C_im[pidx];
        cre[n] = (float)(2.0 * (Cr * Fr - Ci * Fi));
        cim[n] = (float)(2.0 * (Cr * Fi + Ci * Fr));
        double qr = wre, qi = wim;
        #pragma unroll
        for (int s = 0; s < 7; s++) {
            double nr = qr * qr - qi * qi;
            qi = 2.0 * qr * qi; qr = nr;
        }
        float wTr = (float)qr, wTi = (float)qi;
        #pragma unroll
        for (int s = 0; s < 3; s++) {
            double nr = qr * qr - qi * qi;
            qi = 2.0 * qr * qi; qr = nr;
        }
        float* wt = wT_tab + ph * 128 + n * 4;
        wt[0] = wTr; wt[1] = wTi; wt[2] = (float)qr; wt[3] = (float)qi;
    }
    __syncthreads();

    const double TWO_PI  = 6.2831853071795864769;
    const double INV_2PI = 0.15915494309189533577;
    for (int e = tid; e < 129 * 32; e += 256) {
        int j = e >> 5, n = e & 31;
        double phd = (double)j * sdAi[n];
        double r   = fma(-TWO_PI, nearbyint(phd * INV_2PI), phd);
        float  mag = __expf((float)((double)j * sdAr[n]));
        float  rf  = (float)r;
        Pr[j][n] = mag * cosf(rf);
        Pi[j][n] = mag * sinf(rf);
    }
    __syncthreads();

    if (tid < 128) {
        int d = tid;
        float s = 0.f;
        #pragma unroll 8
        for (int n = 0; n < 32; n++)
            s += cre[n] * Pr[d][n] - cim[n] * Pi[d][n];
        if (d == 0) s += Dvec[ph];
        Kv[d] = s;
    }
    __syncthreads();

    _Float16* wpb = Wp + (size_t)ph * 8192;
    for (int e = tid; e < 8192; e += 256) {
        int kk = e >> 7, l = e & 127;
        float v = (kk < 32) ? Pr[127 - l][kk] : Pi[127 - l][kk - 32];
        wpb[e] = (_Float16)v;
    }
    _Float16* a2b = A2 + (size_t)ph * 24576;
    for (int e = tid; e < 24576; e += 256) {
        int m = e / 192, k = e - m * 192;
        float v;
        if (k < 128) {
            v = (k <= m) ? Kv[m - k] : 0.f;
        } else {
            int kk = k - 128, n2 = kk & 31;
            float pr = Pr[m + 1][n2], pi2 = Pi[m + 1][n2];
            v = (kk < 32) ? (cre[n2] * pr - cim[n2] * pi2)
                          : -(cre[n2] * pi2 + cim[n2] * pr);
        }
        a2b[e] = (_Float16)v;
    }
}

// ---------------------------------------------------------------------------
// k_scan: fp16 MFMA DSSM layer, in-place on u16[bh][16384]. Layer 0 fuses the
// input stage (dB -> linear -> tanh) reading x directly. 80 KB LDS, 2 WG/CU.
// ---------------------------------------------------------------------------
__global__ __launch_bounds__(512, 4)
void k_scan(const float* __restrict__ x, _Float16* __restrict__ u16,
            const _Float16* __restrict__ Wp_all, const _Float16* __restrict__ A2_all,
            const float* __restrict__ wT_all, int layer,
            const float* __restrict__ w_in, const float* __restrict__ b_in) {
    extern __shared__ char smem[];
    _Float16* UT = (_Float16*)(smem + UT_OFF);   // [128][192]
    float*    Sf = (float*)(smem + SF_OFF);      // [64][128] swizzled
    float*   yst = (float*)(smem + YST_OFF);     // [128][132] overlay

    const int bh = blockIdx.x;
    const int h  = bh & 63;
    const int tid = threadIdx.x;
    const int lane = tid & 63;
    const int wave = tid >> 6;               // 0..7
    const int ph = layer * 64 + h;
    const _Float16* Wp = Wp_all + (size_t)ph * 8192;
    const _Float16* A2 = A2_all + (size_t)ph * 24576;
    const float* wT4 = wT_all + ph * 128;
    _Float16* uu = u16 + ((size_t)bh << 14);

    const int rA = lane & 15;     // fragment row/col index
    const int qA = lane >> 4;     // fragment k-group

    // ---- stage -> UT (fp16), XOR-swizzled ----
    if (layer == 0) {
        const float* xb = x + ((size_t)(bh >> 6) << 14);
        const float wi = w_in[h], bi = b_in[h];
        for (int it = 0; it < 4; ++it) {
            int flat8 = (it * 512 + tid) * 8;
            int n = flat8 >> 7, k = flat8 & 127;
            float4 a = *(const float4*)(xb + flat8);
            float4 b = *(const float4*)(xb + flat8 + 4);
            float f[8] = {a.x, a.y, a.z, a.w, b.x, b.y, b.z, b.w};
            f16x8 hv;
            #pragma unroll
            for (int j = 0; j < 8; j++) {
                float s = 6.0205999132796239f * __log2f(fabsf(f[j]) + 1e-5f);
                hv[j] = (_Float16)fast_tanh(fmaf(s, wi, bi));
            }
            int kb = (k * 2) ^ ((n & 7) << 4);
            *(f16x8*)((char*)UT + n * 384 + kb) = hv;
        }
    } else {
        for (int it = 0; it < 4; ++it) {
            int flat8 = (it * 512 + tid) * 8;
            int n = flat8 >> 7, k = flat8 & 127;
            f16x8 hv = *(const f16x8*)(uu + flat8);
            int kb = (k * 2) ^ ((n & 7) << 4);
            *(f16x8*)((char*)UT + n * 384 + kb) = hv;
        }
    }
    __syncthreads();

    // ---- GEMM1: Sf[64][128] = Wp . U  (8 waves: 4 m-tiles x 2 nt-halves) ----
    {
        f32x4 acc1[4];
        #pragma unroll
        for (int nt = 0; nt < 4; nt++) acc1[nt] = (f32x4){0.f, 0.f, 0.f, 0.f};
        const int mt1 = wave & 3;
        const int nh  = (wave >> 2) * 4;
        for (int ks = 0; ks < 4; ks++) {
            f16x8 af = *(const f16x8*)(Wp + (mt1 * 16 + rA) * 128 + ks * 32 + qA * 8);
            #pragma unroll
            for (int nt = 0; nt < 4; nt++) {
                int n = (nh + nt) * 16 + rA;
                int kb = (ks * 64 + qA * 16) ^ ((n & 7) << 4);
                f16x8 bv = *(const f16x8*)((char*)UT + n * 384 + kb);
                acc1[nt] = MFMA16F(af, bv, acc1[nt]);
            }
        }
        #pragma unroll
        for (int nt = 0; nt < 4; nt++) {
            int c = (nh + nt) * 16 + rA;
            #pragma unroll
            for (int r = 0; r < 4; r++)
                Sf[SF(mt1 * 16 + qA * 4 + r, c)] = acc1[nt][r];
        }
    }
    __syncthreads();

    // ---- cross-chunk scan, register-resident ----
    {
        const int sn = tid >> 4;
        const int ss = tid & 15;
        const float wTr = wT4[sn * 4 + 0], wTi = wT4[sn * 4 + 1];
        float fr[8], fi[8];
        #pragma unroll
        for (int i = 0; i < 8; i++) {
            fr[i] = Sf[SF(sn,      ss * 8 + i)];
            fi[i] = Sf[SF(sn + 32, ss * 8 + i)];
        }
        float Tr = 0.f, Ti = 0.f;
        #pragma unroll
        for (int i = 0; i < 8; i++) {
            float nTr = fmaf(wTr, Tr, fmaf(-wTi, Ti, fr[i]));
            Ti = fmaf(wTr, Ti, fmaf(wTi, Tr, fi[i]));
            Tr = nTr;
        }
        float gr = wT4[sn * 4 + 2], gi = wT4[sn * 4 + 3];   // wT^8
        #pragma unroll
        for (int s = 0; s < 4; s++) {
            float pr = __shfl_up(Tr, 1 << s, 16);
            float pi = __shfl_up(Ti, 1 << s, 16);
            if (ss >= (1 << s)) {
                Tr = fmaf(gr, pr, fmaf(-gi, pi, Tr));
                Ti = fmaf(gr, pi, fmaf(gi, pr, Ti));
            }
            float ngr = fmaf(gr, gr, -gi * gi);
            gi = 2.f * gr * gi; gr = ngr;
        }
        float Er_ = __shfl_up(Tr, 1, 16);
        float Ei_ = __shfl_up(Ti, 1, 16);
        if (ss == 0) { Er_ = 0.f; Ei_ = 0.f; }
        float Gr = Er_, Gi = Ei_;
        #pragma unroll
        for (int i = 0; i < 8; i++) {
            Sf[SF(sn,      ss * 8 + i)] = Gr;
            Sf[SF(sn + 32, ss * 8 + i)] = Gi;
            float nGr = fmaf(wTr, Gr, fmaf(-wTi, Gi, fr[i]));
            Gi = fmaf(wTr, Gi, fmaf(wTi, Gr, fi[i]));
            Gr = nGr;
        }
    }
    __syncthreads();

    // ---- convert T_init -> UT S-region (fp16, swizzled) ----
    for (int e = tid; e < 8192; e += 512) {
        int kk = e >> 7, c = e & 127;
        float v = Sf[SF(kk, c)];
        int kb = (256 + kk * 2) ^ ((c & 7) << 4);
        *(_Float16*)((char*)UT + c * 384 + kb) = (_Float16)v;
    }
    __syncthreads();

    // ---- GEMM2: Y[128][128] = A2[128][192] . [U; S]  (1 m-tile per wave) ----
    f32x4 acc[8];
    #pragma unroll
    for (int nt = 0; nt < 8; nt++) acc[nt] = (f32x4){0.f, 0.f, 0.f, 0.f};
    for (int ks = 0; ks < 6; ks++) {
        f16x8 a0 = *(const f16x8*)(A2 + (wave * 16 + rA) * 192 + ks * 32 + qA * 8);
        #pragma unroll
        for (int nt = 0; nt < 8; nt++) {
            int n = nt * 16 + rA;
            int kb = (ks * 64 + qA * 16) ^ ((n & 7) << 4);
            f16x8 bv = *(const f16x8*)((char*)UT + n * 384 + kb);
            acc[nt] = MFMA16F(a0, bv, acc[nt]);
        }
    }
    __syncthreads();   // all UT/Sf reads done; yst overlays them

    // ---- epilogue: tanh -> yst[chunk][l_in_chunk], then coalesced fp16 store
    {
        int m_base = wave * 16 + qA * 4;
        #pragma unroll
        for (int nt = 0; nt < 8; nt++) {
            int c = nt * 16 + rA;
            float4 o;
            o.x = fast_tanh(acc[nt][0]);
            o.y = fast_tanh(acc[nt][1]);
            o.z = fast_tanh(acc[nt][2]);
            o.w = fast_tanh(acc[nt][3]);
            *(float4*)(yst + c * 132 + m_base) = o;
        }
    }
    __syncthreads();
    for (int e = tid; e < 2048; e += 512) {
        int c = e >> 4, l8 = e & 15;
        float4 v0 = *(const float4*)(yst + c * 132 + l8 * 8);
        float4 v1 = *(const float4*)(yst + c * 132 + l8 * 8 + 4);
        f16x8 hv;
        hv[0] = (_Float16)v0.x; hv[1] = (_Float16)v0.y;
        hv[2] = (_Float16)v0.z; hv[3] = (_Float16)v0.w;
        hv[4] = (_Float16)v1.x; hv[5] = (_Float16)v1.y;
        hv[6] = (_Float16)v1.z; hv[7] = (_Float16)v1.w;
        *(f16x8*)(uu + c * 128 + l8 * 8) = hv;
    }
}

// ---------------------------------------------------------------------------
// k_linear: in-place channel-mix + tanh, fp16 I/O, f32 math
// ---------------------------------------------------------------------------
__global__ __launch_bounds__(256)
void k_linear(_Float16* __restrict__ uio, const float* __restrict__ W,
              const float* __restrict__ bias) {
    __shared__ float Wt[64][68];
    __shared__ float Ut[64][64];
    const int b  = blockIdx.y;
    const int l0 = blockIdx.x * 64;
    const int tid = threadIdx.x;

    for (int idx = tid; idx < 4096; idx += 256) {
        int o = idx >> 6, hh = idx & 63;
        Wt[hh][o] = W[idx];
        Ut[o][hh] = (float)uio[(((size_t)(b << 6) | o) << 14) + l0 + hh];
    }
    __syncthreads();

    float acc[4][4];
    #pragma unroll
    for (int j = 0; j < 4; j++)
        #pragma unroll
        for (int k = 0; k < 4; k++) acc[j][k] = 0.f;

    const int og = (tid >> 4) << 2;
    const int lg = (tid & 15) << 2;

    #pragma unroll 4
    for (int hh = 0; hh < 64; ++hh) {
        float4 wv = *(const float4*)&Wt[hh][og];
        float4 uv = *(const float4*)&Ut[hh][lg];
        acc[0][0] = fmaf(wv.x, uv.x, acc[0][0]); acc[0][1] = fmaf(wv.x, uv.y, acc[0][1]);
        acc[0][2] = fmaf(wv.x, uv.z, acc[0][2]); acc[0][3] = fmaf(wv.x, uv.w, acc[0][3]);
        acc[1][0] = fmaf(wv.y, uv.x, acc[1][0]); acc[1][1] = fmaf(wv.y, uv.y, acc[1][1]);
        acc[1][2] = fmaf(wv.y, uv.z, acc[1][2]); acc[1][3] = fmaf(wv.y, uv.w, acc[1][3]);
        acc[2][0] = fmaf(wv.z, uv.x, acc[2][0]); acc[2][1] = fmaf(wv.z, uv.y, acc[2][1]);
        acc[2][2] = fmaf(wv.z, uv.z, acc[2][2]); acc[2][3] = fmaf(wv.z, uv.w, acc[2][3]);
        acc[3][0] = fmaf(wv.w, uv.x, acc[3][0]); acc[3][1] = fmaf(wv.w, uv.y, acc[3][1]);
        acc[3][2] = fmaf(wv.w, uv.z, acc[3][2]); acc[3][3] = fmaf(wv.w, uv.w, acc[3][3]);
    }

    #pragma unroll
    for (int j = 0; j < 4; j++) {
        float bo = bias[og + j];
        f16x4 o4;
        o4[0] = (_Float16)fast_tanh(acc[j][0] + bo);
        o4[1] = (_Float16)fast_tanh(acc[j][1] + bo);
        o4[2] = (_Float16)fast_tanh(acc[j][2] + bo);
        o4[3] = (_Float16)fast_tanh(acc[j][3] + bo);
        *(f16x4*)&uio[(((size_t)(b << 6) | (og + j)) << 14) + l0 + lg] = o4;
    }
}

// ---------------------------------------------------------------------------
// k_out: out[b,l] = x[b,l] * 10^((sum_h w_out[h]*u16[b,h,l] + b_out)/20)
// ---------------------------------------------------------------------------
__global__ __launch_bounds__(256)
void k_out(const _Float16* __restrict__ u16, const float* __restrict__ x,
           const float* __restrict__ w_out, const float* __restrict__ b_out,
           float* __restrict__ out) {
    int idx = blockIdx.x * 256 + threadIdx.x;
    int b = idx >> 14;
    int l = idx & (Lq - 1);
    const _Float16* up = u16 + ((size_t)b << 20) + l;
    float acc = 0.f;
    #pragma unroll 8
    for (int hh = 0; hh < 64; ++hh)
        acc = fmaf(w_out[hh], (float)up[(size_t)hh << 14], acc);
    float g = acc + b_out[0];
    out[idx] = x[idx] * exp2f(g * 0.16609640474436812f);
}

// ---------------------------------------------------------------------------
extern "C" void kernel_launch(void* const* d_in, const int* in_sizes, int n_in,
                              void* d_out, int out_size, void* d_ws, size_t ws_size,
                              hipStream_t stream) {
    const float* x          = (const float*)d_in[0];
    const float* w_in       = (const float*)d_in[1];
    const float* b_in       = (const float*)d_in[2];
    const float* w_mid      = (const float*)d_in[3];
    const float* b_mid      = (const float*)d_in[4];
    const float* w_out      = (const float*)d_in[5];
    const float* b_out      = (const float*)d_in[6];
    const float* log_dt     = (const float*)d_in[7];
    const float* log_A_real = (const float*)d_in[8];
    const float* A_imag     = (const float*)d_in[9];
    const float* C_re       = (const float*)d_in[10];
    const float* C_im       = (const float*)d_in[11];
    const float* Dv         = (const float*)d_in[12];

    char* ws = (char*)d_ws;
    float*     wT_tab = (float*)(ws + WT_OFF_B);
    _Float16*  Wp     = (_Float16*)(ws + WP_OFF_B);
    _Float16*  A2     = (_Float16*)(ws + A2_OFF_B);
    _Float16*  u16    = (_Float16*)(ws + U_OFF_B);
    float* out = (float*)d_out;

    hipFuncSetAttribute((const void*)k_scan,
                        hipFuncAttributeMaxDynamicSharedMemorySize, SMEM_SZ);

    k_prep<<<NLAYERSq * Hq, 256, 0, stream>>>(log_dt, log_A_real, A_imag,
                                              C_re, C_im, Dv, wT_tab, Wp, A2);
    for (int layer = 0; layer < NLAYERSq; layer++) {
        if (layer > 0)
            k_linear<<<dim3(Lq / 64, Bq), 256, 0, stream>>>(
                u16, w_mid + (size_t)(layer - 1) * Hq * Hq, b_mid + (size_t)(layer - 1) * Hq);
        k_scan<<<Bq * Hq, 512, SMEM_SZ, stream>>>(x, u16, Wp, A2, wT_tab, layer,
                                                  w_in, b_in);
    }
    k_out<<<(Bq * Lq) / 256, 256, 0, stream>>>(u16, x, w_out, b_out, out);
}

// Round 9
// 184.338 us; speedup vs baseline: 2.4464x; 1.1654x over previous
//
#include <hip/hip_runtime.h>
#include <math.h>

#define Bq 8
#define Lq 16384
#define Hq 64
#define N2q 32
#define NLAYERSq 5

typedef _Float16 f16x8 __attribute__((ext_vector_type(8)));
typedef _Float16 f16x4 __attribute__((ext_vector_type(4)));
typedef float    f32x4 __attribute__((ext_vector_type(4)));

#define MFMA16F(a, b, c) __builtin_amdgcn_mfma_f32_16x16x32_f16(a, b, c, 0, 0, 0)

// ---- LDS layout for k_scan (dynamic): exactly 80 KB -> 2 WG/CU ----
#define UT_OFF    0           // _Float16 [128][192]  48 KB  ([U | S])
#define SF_OFF    49152       // float    [64][128]   32 KB  (XOR-swizzled)
#define SMEM_SZ   81920
#define YST_OFF   0           // float [128][132] overlays UT+Sf after GEMM2
#define SF(row, c) ((row) * 128 + ((c) ^ ((row) & 31)))

// ---- workspace layout (bytes) ----
#define WT_OFF_B   0                        // f32 [320][32][4]
#define WP_OFF_B   163840                   // f16 [320][64][128]
#define A2_OFF_B   (163840 + 5242880)       // f16 [320][128][192]
#define W16_OFF_B  (163840 + 5242880 + 15728640)          // f16 [4][64][64]
#define U_OFF_B    (163840 + 5242880 + 15728640 + 32768)  // f16 [512][16384]

__device__ __forceinline__ float fast_tanh(float y) {
    float e = __expf(2.0f * y);
    return 1.0f - 2.0f * __builtin_amdgcn_rcpf(e + 1.0f);
}

// ---------------------------------------------------------------------------
// k_prep: per (layer,h) coefficient tables (fp16) + fp16 copy of w_mid.
// ---------------------------------------------------------------------------
__global__ __launch_bounds__(256)
void k_prep(const float* __restrict__ log_dt, const float* __restrict__ log_A_real,
            const float* __restrict__ A_imag, const float* __restrict__ C_re,
            const float* __restrict__ C_im, const float* __restrict__ Dvec,
            const float* __restrict__ w_mid,
            float* __restrict__ wT_tab, _Float16* __restrict__ Wp,
            _Float16* __restrict__ A2, _Float16* __restrict__ W16) {
    __shared__ float Pr[129][33], Pi[129][33];
    __shared__ float cre[32], cim[32], Kv[128];
    __shared__ double sdAr[32], sdAi[32];
    const int ph = blockIdx.x;          // layer*64 + h
    const int tid = threadIdx.x;

    // fp16 copy of w_mid (first 256 blocks convert 64 elems each)
    if (ph < 256 && tid < 64) {
        int e = ph * 64 + tid;
        W16[e] = (_Float16)w_mid[e];
    }

    if (tid < 32) {
        int n = tid;
        int pidx = ph * N2q + n;
        double dt  = exp((double)log_dt[ph]);
        double aRe = -exp((double)log_A_real[pidx]);
        double aIm = (double)A_imag[pidx];
        double dAr = aRe * dt, dAi = aIm * dt;
        sdAr[n] = dAr; sdAi[n] = dAi;
        double er  = exp(dAr);
        double wre = er * cos(dAi), wim = er * sin(dAi);
        double Er = wre - 1.0, Ei = wim;
        double inv = 1.0 / (aRe * aRe + aIm * aIm);
        double Fr = (Er * aRe + Ei * aIm) * inv;
        double Fi = (Ei * aRe - Er * aIm) * inv;
        double Cr = (double)C_re[pidx], Ci = (double)C_im[pidx];
        cre[n] = (float)(2.0 * (Cr * Fr - Ci * Fi));
        cim[n] = (float)(2.0 * (Cr * Fi + Ci * Fr));
        double qr = wre, qi = wim;
        #pragma unroll
        for (int s = 0; s < 7; s++) {
            double nr = qr * qr - qi * qi;
            qi = 2.0 * qr * qi; qr = nr;
        }
        float wTr = (float)qr, wTi = (float)qi;
        #pragma unroll
        for (int s = 0; s < 3; s++) {
            double nr = qr * qr - qi * qi;
            qi = 2.0 * qr * qi; qr = nr;
        }
        float* wt = wT_tab + ph * 128 + n * 4;
        wt[0] = wTr; wt[1] = wTi; wt[2] = (float)qr; wt[3] = (float)qi;
    }
    __syncthreads();

    const double TWO_PI  = 6.2831853071795864769;
    const double INV_2PI = 0.15915494309189533577;
    for (int e = tid; e < 129 * 32; e += 256) {
        int j = e >> 5, n = e & 31;
        double phd = (double)j * sdAi[n];
        double r   = fma(-TWO_PI, nearbyint(phd * INV_2PI), phd);
        float  mag = __expf((float)((double)j * sdAr[n]));
        float  rf  = (float)r;
        Pr[j][n] = mag * cosf(rf);
        Pi[j][n] = mag * sinf(rf);
    }
    __syncthreads();

    if (tid < 128) {
        int d = tid;
        float s = 0.f;
        #pragma unroll 8
        for (int n = 0; n < 32; n++)
            s += cre[n] * Pr[d][n] - cim[n] * Pi[d][n];
        if (d == 0) s += Dvec[ph];
        Kv[d] = s;
    }
    __syncthreads();

    _Float16* wpb = Wp + (size_t)ph * 8192;
    for (int e = tid; e < 8192; e += 256) {
        int kk = e >> 7, l = e & 127;
        float v = (kk < 32) ? Pr[127 - l][kk] : Pi[127 - l][kk - 32];
        wpb[e] = (_Float16)v;
    }
    _Float16* a2b = A2 + (size_t)ph * 24576;
    for (int e = tid; e < 24576; e += 256) {
        int m = e / 192, k = e - m * 192;
        float v;
        if (k < 128) {
            v = (k <= m) ? Kv[m - k] : 0.f;
        } else {
            int kk = k - 128, n2 = kk & 31;
            float pr = Pr[m + 1][n2], pi2 = Pi[m + 1][n2];
            v = (kk < 32) ? (cre[n2] * pr - cim[n2] * pi2)
                          : -(cre[n2] * pi2 + cim[n2] * pr);
        }
        a2b[e] = (_Float16)v;
    }
}

// ---------------------------------------------------------------------------
// k_scan: fp16 MFMA DSSM layer, in-place on u16[bh][16384]. Layer 0 fuses the
// input stage (dB -> linear -> tanh) reading x directly. 80 KB LDS, 2 WG/CU.
// ---------------------------------------------------------------------------
__global__ __launch_bounds__(512, 4)
void k_scan(const float* __restrict__ x, _Float16* __restrict__ u16,
            const _Float16* __restrict__ Wp_all, const _Float16* __restrict__ A2_all,
            const float* __restrict__ wT_all, int layer,
            const float* __restrict__ w_in, const float* __restrict__ b_in) {
    extern __shared__ char smem[];
    _Float16* UT = (_Float16*)(smem + UT_OFF);   // [128][192]
    float*    Sf = (float*)(smem + SF_OFF);      // [64][128] swizzled
    float*   yst = (float*)(smem + YST_OFF);     // [128][132] overlay

    const int bh = blockIdx.x;
    const int h  = bh & 63;
    const int tid = threadIdx.x;
    const int lane = tid & 63;
    const int wave = tid >> 6;               // 0..7
    const int ph = layer * 64 + h;
    const _Float16* Wp = Wp_all + (size_t)ph * 8192;
    const _Float16* A2 = A2_all + (size_t)ph * 24576;
    const float* wT4 = wT_all + ph * 128;
    _Float16* uu = u16 + ((size_t)bh << 14);

    const int rA = lane & 15;     // fragment row/col index
    const int qA = lane >> 4;     // fragment k-group

    // ---- stage -> UT (fp16), XOR-swizzled ----
    if (layer == 0) {
        const float* xb = x + ((size_t)(bh >> 6) << 14);
        const float wi = w_in[h], bi = b_in[h];
        for (int it = 0; it < 4; ++it) {
            int flat8 = (it * 512 + tid) * 8;
            int n = flat8 >> 7, k = flat8 & 127;
            float4 a = *(const float4*)(xb + flat8);
            float4 b = *(const float4*)(xb + flat8 + 4);
            float f[8] = {a.x, a.y, a.z, a.w, b.x, b.y, b.z, b.w};
            f16x8 hv;
            #pragma unroll
            for (int j = 0; j < 8; j++) {
                float s = 6.0205999132796239f * __log2f(fabsf(f[j]) + 1e-5f);
                hv[j] = (_Float16)fast_tanh(fmaf(s, wi, bi));
            }
            int kb = (k * 2) ^ ((n & 7) << 4);
            *(f16x8*)((char*)UT + n * 384 + kb) = hv;
        }
    } else {
        for (int it = 0; it < 4; ++it) {
            int flat8 = (it * 512 + tid) * 8;
            int n = flat8 >> 7, k = flat8 & 127;
            f16x8 hv = *(const f16x8*)(uu + flat8);
            int kb = (k * 2) ^ ((n & 7) << 4);
            *(f16x8*)((char*)UT + n * 384 + kb) = hv;
        }
    }
    __syncthreads();

    // ---- GEMM1: Sf[64][128] = Wp . U  (8 waves: 4 m-tiles x 2 nt-halves) ----
    {
        f32x4 acc1[4];
        #pragma unroll
        for (int nt = 0; nt < 4; nt++) acc1[nt] = (f32x4){0.f, 0.f, 0.f, 0.f};
        const int mt1 = wave & 3;
        const int nh  = (wave >> 2) * 4;
        for (int ks = 0; ks < 4; ks++) {
            f16x8 af = *(const f16x8*)(Wp + (mt1 * 16 + rA) * 128 + ks * 32 + qA * 8);
            #pragma unroll
            for (int nt = 0; nt < 4; nt++) {
                int n = (nh + nt) * 16 + rA;
                int kb = (ks * 64 + qA * 16) ^ ((n & 7) << 4);
                f16x8 bv = *(const f16x8*)((char*)UT + n * 384 + kb);
                acc1[nt] = MFMA16F(af, bv, acc1[nt]);
            }
        }
        #pragma unroll
        for (int nt = 0; nt < 4; nt++) {
            int c = (nh + nt) * 16 + rA;
            #pragma unroll
            for (int r = 0; r < 4; r++)
                Sf[SF(mt1 * 16 + qA * 4 + r, c)] = acc1[nt][r];
        }
    }
    __syncthreads();

    // ---- cross-chunk scan, register-resident ----
    {
        const int sn = tid >> 4;
        const int ss = tid & 15;
        const float wTr = wT4[sn * 4 + 0], wTi = wT4[sn * 4 + 1];
        float fr[8], fi[8];
        #pragma unroll
        for (int i = 0; i < 8; i++) {
            fr[i] = Sf[SF(sn,      ss * 8 + i)];
            fi[i] = Sf[SF(sn + 32, ss * 8 + i)];
        }
        float Tr = 0.f, Ti = 0.f;
        #pragma unroll
        for (int i = 0; i < 8; i++) {
            float nTr = fmaf(wTr, Tr, fmaf(-wTi, Ti, fr[i]));
            Ti = fmaf(wTr, Ti, fmaf(wTi, Tr, fi[i]));
            Tr = nTr;
        }
        float gr = wT4[sn * 4 + 2], gi = wT4[sn * 4 + 3];   // wT^8
        #pragma unroll
        for (int s = 0; s < 4; s++) {
            float pr = __shfl_up(Tr, 1 << s, 16);
            float pi = __shfl_up(Ti, 1 << s, 16);
            if (ss >= (1 << s)) {
                Tr = fmaf(gr, pr, fmaf(-gi, pi, Tr));
                Ti = fmaf(gr, pi, fmaf(gi, pr, Ti));
            }
            float ngr = fmaf(gr, gr, -gi * gi);
            gi = 2.f * gr * gi; gr = ngr;
        }
        float Er_ = __shfl_up(Tr, 1, 16);
        float Ei_ = __shfl_up(Ti, 1, 16);
        if (ss == 0) { Er_ = 0.f; Ei_ = 0.f; }
        float Gr = Er_, Gi = Ei_;
        #pragma unroll
        for (int i = 0; i < 8; i++) {
            Sf[SF(sn,      ss * 8 + i)] = Gr;
            Sf[SF(sn + 32, ss * 8 + i)] = Gi;
            float nGr = fmaf(wTr, Gr, fmaf(-wTi, Gi, fr[i]));
            Gi = fmaf(wTr, Gi, fmaf(wTi, Gr, fi[i]));
            Gr = nGr;
        }
    }
    __syncthreads();

    // ---- convert T_init -> UT S-region (fp16, swizzled) ----
    for (int e = tid; e < 8192; e += 512) {
        int kk = e >> 7, c = e & 127;
        float v = Sf[SF(kk, c)];
        int kb = (256 + kk * 2) ^ ((c & 7) << 4);
        *(_Float16*)((char*)UT + c * 384 + kb) = (_Float16)v;
    }
    __syncthreads();

    // ---- GEMM2: Y[128][128] = A2[128][192] . [U; S]  (1 m-tile per wave) ----
    f32x4 acc[8];
    #pragma unroll
    for (int nt = 0; nt < 8; nt++) acc[nt] = (f32x4){0.f, 0.f, 0.f, 0.f};
    for (int ks = 0; ks < 6; ks++) {
        f16x8 a0 = *(const f16x8*)(A2 + (wave * 16 + rA) * 192 + ks * 32 + qA * 8);
        #pragma unroll
        for (int nt = 0; nt < 8; nt++) {
            int n = nt * 16 + rA;
            int kb = (ks * 64 + qA * 16) ^ ((n & 7) << 4);
            f16x8 bv = *(const f16x8*)((char*)UT + n * 384 + kb);
            acc[nt] = MFMA16F(a0, bv, acc[nt]);
        }
    }
    __syncthreads();   // all UT/Sf reads done; yst overlays them

    // ---- epilogue: tanh -> yst, then coalesced fp16 store ----
    {
        int m_base = wave * 16 + qA * 4;
        #pragma unroll
        for (int nt = 0; nt < 8; nt++) {
            int c = nt * 16 + rA;
            float4 o;
            o.x = fast_tanh(acc[nt][0]);
            o.y = fast_tanh(acc[nt][1]);
            o.z = fast_tanh(acc[nt][2]);
            o.w = fast_tanh(acc[nt][3]);
            *(float4*)(yst + c * 132 + m_base) = o;
        }
    }
    __syncthreads();
    for (int e = tid; e < 2048; e += 512) {
        int c = e >> 4, l8 = e & 15;
        float4 v0 = *(const float4*)(yst + c * 132 + l8 * 8);
        float4 v1 = *(const float4*)(yst + c * 132 + l8 * 8 + 4);
        f16x8 hv;
        hv[0] = (_Float16)v0.x; hv[1] = (_Float16)v0.y;
        hv[2] = (_Float16)v0.z; hv[3] = (_Float16)v0.w;
        hv[4] = (_Float16)v1.x; hv[5] = (_Float16)v1.y;
        hv[6] = (_Float16)v1.z; hv[7] = (_Float16)v1.w;
        *(f16x8*)(uu + c * 128 + l8 * 8) = hv;
    }
}

// ---------------------------------------------------------------------------
// k_linear: MFMA channel-mix + tanh, fp16 in-place.
// Block = (b, 256-l tile). C[64 o][256 l] = W16[64][64] . U[64 h][256 l].
// U staged transposed in LDS as Ul[l][h] (B-operand layout, XOR-swizzled).
// ---------------------------------------------------------------------------
__global__ __launch_bounds__(256, 4)
void k_linear(_Float16* __restrict__ uio, const _Float16* __restrict__ W16,
              const float* __restrict__ bias) {
    __shared__ __align__(16) char lmem[33792];
    _Float16* Ul  = (_Float16*)lmem;     // [256 l][64 h], row 128 B, swizzled
    _Float16* yst = (_Float16*)lmem;     // [64 o][264 l] overlay after GEMM

    const int b   = blockIdx.y;
    const int l0  = blockIdx.x * 256;
    const int tid = threadIdx.x;
    const int lane = tid & 63;
    const int wave = tid >> 6;      // m-tile 0..3
    const int rA = lane & 15;
    const int qA = lane >> 4;

    _Float16* ub = uio + ((size_t)b << 20) + l0;   // + b*64*16384

    // ---- stage: Ul[l][h] via h-pair packed b32 writes ----
    for (int it = 0; it < 4; ++it) {
        int g  = it * 256 + tid;     // 0..1023
        int hp = g >> 5;             // h-pair 0..31
        int l8 = g & 31;             // l-octet 0..31
        f16x8 v0 = *(const f16x8*)(ub + (size_t)(hp * 2)     * Lq + l8 * 8);
        f16x8 v1 = *(const f16x8*)(ub + (size_t)(hp * 2 + 1) * Lq + l8 * 8);
        const unsigned short* p0 = (const unsigned short*)&v0;
        const unsigned short* p1 = (const unsigned short*)&v1;
        int sw = (l8 & 7) << 4;
        #pragma unroll
        for (int j = 0; j < 8; j++) {
            unsigned int pk = (unsigned int)p0[j] | ((unsigned int)p1[j] << 16);
            *(unsigned int*)((char*)Ul + (l8 * 8 + j) * 128 + ((hp * 4) ^ sw)) = pk;
        }
    }
    __syncthreads();

    // ---- GEMM: 4 waves x (1 m-tile x 16 n-tiles x K=64) ----
    f32x4 acc[16];
    #pragma unroll
    for (int nt = 0; nt < 16; nt++) acc[nt] = (f32x4){0.f, 0.f, 0.f, 0.f};
    const _Float16* Wrow = W16 + (wave * 16 + rA) * 64;
    #pragma unroll
    for (int kf = 0; kf < 2; kf++) {
        f16x8 af = *(const f16x8*)(Wrow + kf * 32 + qA * 8);
        #pragma unroll
        for (int nt = 0; nt < 16; nt++) {
            int n = nt * 16 + rA;
            int sw = ((n >> 3) & 7) << 4;
            f16x8 bv = *(const f16x8*)((char*)Ul + n * 128 + ((kf * 64 + qA * 16) ^ sw));
            acc[nt] = MFMA16F(af, bv, acc[nt]);
        }
    }
    __syncthreads();   // all Ul reads done; yst overlays

    // ---- epilogue: bias + tanh -> yst[o][l], then coalesced store ----
    {
        int ob = wave * 16 + qA * 4;
        float bo0 = bias[ob], bo1 = bias[ob + 1], bo2 = bias[ob + 2], bo3 = bias[ob + 3];
        #pragma unroll
        for (int nt = 0; nt < 16; nt++) {
            int l = nt * 16 + rA;
            yst[(ob + 0) * 264 + l] = (_Float16)fast_tanh(acc[nt][0] + bo0);
            yst[(ob + 1) * 264 + l] = (_Float16)fast_tanh(acc[nt][1] + bo1);
            yst[(ob + 2) * 264 + l] = (_Float16)fast_tanh(acc[nt][2] + bo2);
            yst[(ob + 3) * 264 + l] = (_Float16)fast_tanh(acc[nt][3] + bo3);
        }
    }
    __syncthreads();
    for (int it = 0; it < 8; ++it) {
        int e = it * 256 + tid;      // 0..2047
        int o = e >> 5, l8 = e & 31;
        f16x8 hv = *(const f16x8*)(yst + o * 264 + l8 * 8);
        *(f16x8*)(ub + (size_t)o * Lq + l8 * 8) = hv;
    }
}

// ---------------------------------------------------------------------------
// k_out: out[b,l] = x[b,l] * 10^((sum_h w_out[h]*u16[b,h,l] + b_out)/20)
// ---------------------------------------------------------------------------
__global__ __launch_bounds__(256)
void k_out(const _Float16* __restrict__ u16, const float* __restrict__ x,
           const float* __restrict__ w_out, const float* __restrict__ b_out,
           float* __restrict__ out) {
    int idx = blockIdx.x * 256 + threadIdx.x;
    int b = idx >> 14;
    int l = idx & (Lq - 1);
    const _Float16* up = u16 + ((size_t)b << 20) + l;
    float acc = 0.f;
    #pragma unroll 8
    for (int hh = 0; hh < 64; ++hh)
        acc = fmaf(w_out[hh], (float)up[(size_t)hh << 14], acc);
    float g = acc + b_out[0];
    out[idx] = x[idx] * exp2f(g * 0.16609640474436812f);
}

// ---------------------------------------------------------------------------
extern "C" void kernel_launch(void* const* d_in, const int* in_sizes, int n_in,
                              void* d_out, int out_size, void* d_ws, size_t ws_size,
                              hipStream_t stream) {
    const float* x          = (const float*)d_in[0];
    const float* w_in       = (const float*)d_in[1];
    const float* b_in       = (const float*)d_in[2];
    const float* w_mid      = (const float*)d_in[3];
    const float* b_mid      = (const float*)d_in[4];
    const float* w_out      = (const float*)d_in[5];
    const float* b_out      = (const float*)d_in[6];
    const float* log_dt     = (const float*)d_in[7];
    const float* log_A_real = (const float*)d_in[8];
    const float* A_imag     = (const float*)d_in[9];
    const float* C_re       = (const float*)d_in[10];
    const float* C_im       = (const float*)d_in[11];
    const float* Dv         = (const float*)d_in[12];

    char* ws = (char*)d_ws;
    float*     wT_tab = (float*)(ws + WT_OFF_B);
    _Float16*  Wp     = (_Float16*)(ws + WP_OFF_B);
    _Float16*  A2     = (_Float16*)(ws + A2_OFF_B);
    _Float16*  W16    = (_Float16*)(ws + W16_OFF_B);
    _Float16*  u16    = (_Float16*)(ws + U_OFF_B);
    float* out = (float*)d_out;

    hipFuncSetAttribute((const void*)k_scan,
                        hipFuncAttributeMaxDynamicSharedMemorySize, SMEM_SZ);

    k_prep<<<NLAYERSq * Hq, 256, 0, stream>>>(log_dt, log_A_real, A_imag,
                                              C_re, C_im, Dv, w_mid,
                                              wT_tab, Wp, A2, W16);
    for (int layer = 0; layer < NLAYERSq; layer++) {
        if (layer > 0)
            k_linear<<<dim3(Lq / 256, Bq), 256, 0, stream>>>(
                u16, W16 + (size_t)(layer - 1) * Hq * Hq, b_mid + (size_t)(layer - 1) * Hq);
        k_scan<<<Bq * Hq, 512, SMEM_SZ, stream>>>(x, u16, Wp, A2, wT_tab, layer,
                                                  w_in, b_in);
    }
    k_out<<<(Bq * Lq) / 256, 256, 0, stream>>>(u16, x, w_out, b_out, out);
}

// Round 10
// 176.740 us; speedup vs baseline: 2.5516x; 1.0430x over previous
//
#include <hip/hip_runtime.h>
#include <math.h>

#define Bq 8
#define Lq 16384
#define Hq 64
#define N2q 32
#define NLAYERSq 5

typedef _Float16 f16x8 __attribute__((ext_vector_type(8)));
typedef _Float16 f16x4 __attribute__((ext_vector_type(4)));
typedef float    f32x4 __attribute__((ext_vector_type(4)));

#define MFMA16F(a, b, c) __builtin_amdgcn_mfma_f32_16x16x32_f16(a, b, c, 0, 0, 0)

// ---- LDS layout for k_scan (dynamic): 49 KB ----
#define UT_OFF    0           // f16 [128 chunk][128 pos] swizzled, 32 KB
#define SS_OFF    32768       // Sf16 f16 [64][136] 17408 B; later St16 f16 [128][64] 16 KB
#define SMEM_SZ   50176
#define YST_OFF   0           // f16 [128][136] overlay after GEMM2 (34816 B)

// ---- workspace layout (bytes) ----
#define WT_OFF_B   0                        // f32 [320][32][4]
#define WP_OFF_B   163840                   // f16 [320][64][128]
#define A2_OFF_B   (163840 + 5242880)       // f16 [320][128][192]
#define W16_OFF_B  (163840 + 5242880 + 15728640)          // f16 [4][64][64]
#define U_OFF_B    (163840 + 5242880 + 15728640 + 32768)  // f16 [512][16384]

__device__ __forceinline__ float fast_tanh(float y) {
    float e = __expf(2.0f * y);
    return 1.0f - 2.0f * __builtin_amdgcn_rcpf(e + 1.0f);
}

// ---------------------------------------------------------------------------
// k_prep: per (layer,h) coefficient tables (fp16) + fp16 copy of w_mid.
//   wT_tab [32][4]: (wT.re, wT.im, w16.re, w16.im), wT = w^128, w16 = wT^16
// ---------------------------------------------------------------------------
__global__ __launch_bounds__(256)
void k_prep(const float* __restrict__ log_dt, const float* __restrict__ log_A_real,
            const float* __restrict__ A_imag, const float* __restrict__ C_re,
            const float* __restrict__ C_im, const float* __restrict__ Dvec,
            const float* __restrict__ w_mid,
            float* __restrict__ wT_tab, _Float16* __restrict__ Wp,
            _Float16* __restrict__ A2, _Float16* __restrict__ W16) {
    __shared__ float Pr[129][33], Pi[129][33];
    __shared__ float cre[32], cim[32], Kv[128];
    __shared__ double sdAr[32], sdAi[32];
    const int ph = blockIdx.x;          // layer*64 + h
    const int tid = threadIdx.x;

    if (ph < 256 && tid < 64) {
        int e = ph * 64 + tid;
        W16[e] = (_Float16)w_mid[e];
    }

    if (tid < 32) {
        int n = tid;
        int pidx = ph * N2q + n;
        double dt  = exp((double)log_dt[ph]);
        double aRe = -exp((double)log_A_real[pidx]);
        double aIm = (double)A_imag[pidx];
        double dAr = aRe * dt, dAi = aIm * dt;
        sdAr[n] = dAr; sdAi[n] = dAi;
        double er  = exp(dAr);
        double wre = er * cos(dAi), wim = er * sin(dAi);
        double Er = wre - 1.0, Ei = wim;
        double inv = 1.0 / (aRe * aRe + aIm * aIm);
        double Fr = (Er * aRe + Ei * aIm) * inv;
        double Fi = (Ei * aRe - Er * aIm) * inv;
        double Cr = (double)C_re[pidx], Ci = (double)C_im[pidx];
        cre[n] = (float)(2.0 * (Cr * Fr - Ci * Fi));
        cim[n] = (float)(2.0 * (Cr * Fi + Ci * Fr));
        double qr = wre, qi = wim;
        #pragma unroll
        for (int s = 0; s < 7; s++) {
            double nr = qr * qr - qi * qi;
            qi = 2.0 * qr * qi; qr = nr;
        }
        float wTr = (float)qr, wTi = (float)qi;
        #pragma unroll
        for (int s = 0; s < 4; s++) {    // wT^16
            double nr = qr * qr - qi * qi;
            qi = 2.0 * qr * qi; qr = nr;
        }
        float* wt = wT_tab + ph * 128 + n * 4;
        wt[0] = wTr; wt[1] = wTi; wt[2] = (float)qr; wt[3] = (float)qi;
    }
    __syncthreads();

    const double TWO_PI  = 6.2831853071795864769;
    const double INV_2PI = 0.15915494309189533577;
    for (int e = tid; e < 129 * 32; e += 256) {
        int j = e >> 5, n = e & 31;
        double phd = (double)j * sdAi[n];
        double r   = fma(-TWO_PI, nearbyint(phd * INV_2PI), phd);
        float  mag = __expf((float)((double)j * sdAr[n]));
        float  rf  = (float)r;
        Pr[j][n] = mag * cosf(rf);
        Pi[j][n] = mag * sinf(rf);
    }
    __syncthreads();

    if (tid < 128) {
        int d = tid;
        float s = 0.f;
        #pragma unroll 8
        for (int n = 0; n < 32; n++)
            s += cre[n] * Pr[d][n] - cim[n] * Pi[d][n];
        if (d == 0) s += Dvec[ph];
        Kv[d] = s;
    }
    __syncthreads();

    _Float16* wpb = Wp + (size_t)ph * 8192;
    for (int e = tid; e < 8192; e += 256) {
        int kk = e >> 7, l = e & 127;
        float v = (kk < 32) ? Pr[127 - l][kk] : Pi[127 - l][kk - 32];
        wpb[e] = (_Float16)v;
    }
    _Float16* a2b = A2 + (size_t)ph * 24576;
    for (int e = tid; e < 24576; e += 256) {
        int m = e / 192, k = e - m * 192;
        float v;
        if (k < 128) {
            v = (k <= m) ? Kv[m - k] : 0.f;
        } else {
            int kk = k - 128, n2 = kk & 31;
            float pr = Pr[m + 1][n2], pi2 = Pi[m + 1][n2];
            v = (kk < 32) ? (cre[n2] * pr - cim[n2] * pi2)
                          : -(cre[n2] * pi2 + cim[n2] * pr);
        }
        a2b[e] = (_Float16)v;
    }
}

// ---------------------------------------------------------------------------
// k_scan: fp16 MFMA DSSM layer, in-place on u16[bh][16384]. Layer 0 fuses the
// input stage (dB -> linear -> tanh). 256 thr (4 waves), 49 KB LDS.
// Phases: stage -> GEMM1(->Sf16) -> reg-scan(->St16 direct) -> GEMM2 -> epi.
// ---------------------------------------------------------------------------
__global__ __launch_bounds__(256, 3)
void k_scan(const float* __restrict__ x, _Float16* __restrict__ u16,
            const _Float16* __restrict__ Wp_all, const _Float16* __restrict__ A2_all,
            const float* __restrict__ wT_all, int layer,
            const float* __restrict__ w_in, const float* __restrict__ b_in) {
    extern __shared__ char smem[];
    char* UT = smem + UT_OFF;            // f16 [128][128] swizzled (byte rows 256)
    char* Sf = smem + SS_OFF;            // f16 [64][136]  (byte rows 272)
    char* St = smem + SS_OFF;            // f16 [128][64] swizzled (byte rows 128)
    char* yst = smem + YST_OFF;          // f16 [128][136] overlay

    const int bh = blockIdx.x;
    const int h  = bh & 63;
    const int tid = threadIdx.x;
    const int lane = tid & 63;
    const int wave = tid >> 6;               // 0..3
    const int ph = layer * 64 + h;
    const _Float16* Wp = Wp_all + (size_t)ph * 8192;
    const _Float16* A2 = A2_all + (size_t)ph * 24576;
    const float* wT4 = wT_all + ph * 128;
    _Float16* uu = u16 + ((size_t)bh << 14);

    const int rA = lane & 15;     // fragment row/col index
    const int qA = lane >> 4;     // fragment k-group

    // ---- stage -> UT (fp16), XOR-swizzled: UT[n][k] at n*256 + (2k ^ ((n&7)<<4))
    if (layer == 0) {
        const float* xb = x + ((size_t)(bh >> 6) << 14);
        const float wi = w_in[h], bi = b_in[h];
        for (int it = 0; it < 8; ++it) {
            int flat8 = (it * 256 + tid) * 8;
            int n = flat8 >> 7, k = flat8 & 127;
            float4 a = *(const float4*)(xb + flat8);
            float4 b = *(const float4*)(xb + flat8 + 4);
            float f[8] = {a.x, a.y, a.z, a.w, b.x, b.y, b.z, b.w};
            f16x8 hv;
            #pragma unroll
            for (int j = 0; j < 8; j++) {
                float s = 6.0205999132796239f * __log2f(fabsf(f[j]) + 1e-5f);
                hv[j] = (_Float16)fast_tanh(fmaf(s, wi, bi));
            }
            *(f16x8*)(UT + n * 256 + ((k * 2) ^ ((n & 7) << 4))) = hv;
        }
    } else {
        for (int it = 0; it < 8; ++it) {
            int flat8 = (it * 256 + tid) * 8;
            int n = flat8 >> 7, k = flat8 & 127;
            f16x8 hv = *(const f16x8*)(uu + flat8);
            *(f16x8*)(UT + n * 256 + ((k * 2) ^ ((n & 7) << 4))) = hv;
        }
    }
    __syncthreads();

    // ---- GEMM1: Sf16[64 moderow][128 chunk] = Wp . U  (4 waves x 1 m-tile) ----
    {
        f32x4 acc1[8];
        #pragma unroll
        for (int nt = 0; nt < 8; nt++) acc1[nt] = (f32x4){0.f, 0.f, 0.f, 0.f};
        for (int ks = 0; ks < 4; ks++) {
            f16x8 af = *(const f16x8*)(Wp + (wave * 16 + rA) * 128 + ks * 32 + qA * 8);
            #pragma unroll
            for (int nt = 0; nt < 8; nt++) {
                int n = nt * 16 + rA;
                f16x8 bv = *(const f16x8*)(UT + n * 256 + ((ks * 64 + qA * 16) ^ ((n & 7) << 4)));
                acc1[nt] = MFMA16F(af, bv, acc1[nt]);
            }
        }
        #pragma unroll
        for (int nt = 0; nt < 8; nt++) {
            int c = nt * 16 + rA;
            #pragma unroll
            for (int r = 0; r < 4; r++)
                *(_Float16*)(Sf + (wave * 16 + qA * 4 + r) * 272 + c * 2) = (_Float16)acc1[nt][r];
        }
    }
    __syncthreads();

    // ---- cross-chunk scan: Sf16 -> registers -> St16 (direct, fp16) ----
    {
        const int sn = tid >> 3;        // mode 0..31
        const int ss = tid & 7;         // sub-block of 16 chunks
        const float wTr = wT4[sn * 4 + 0], wTi = wT4[sn * 4 + 1];
        float fr[16], fi[16];
        {
            f16x8 a0 = *(const f16x8*)(Sf + sn * 272 + ss * 32);
            f16x8 a1 = *(const f16x8*)(Sf + sn * 272 + ss * 32 + 16);
            f16x8 b0 = *(const f16x8*)(Sf + (sn + 32) * 272 + ss * 32);
            f16x8 b1 = *(const f16x8*)(Sf + (sn + 32) * 272 + ss * 32 + 16);
            #pragma unroll
            for (int j = 0; j < 8; j++) {
                fr[j] = (float)a0[j]; fr[j + 8] = (float)a1[j];
                fi[j] = (float)b0[j]; fi[j + 8] = (float)b1[j];
            }
        }
        // sub-block total
        float Tr = 0.f, Ti = 0.f;
        #pragma unroll
        for (int i = 0; i < 16; i++) {
            float nTr = fmaf(wTr, Tr, fmaf(-wTi, Ti, fr[i]));
            Ti = fmaf(wTr, Ti, fmaf(wTi, Tr, fi[i]));
            Tr = nTr;
        }
        // Kogge-Stone over 8 sub-blocks, decay wT^16 squared per step
        float gr = wT4[sn * 4 + 2], gi = wT4[sn * 4 + 3];
        #pragma unroll
        for (int s = 0; s < 3; s++) {
            float pr = __shfl_up(Tr, 1 << s, 8);
            float pi = __shfl_up(Ti, 1 << s, 8);
            if (ss >= (1 << s)) {
                Tr = fmaf(gr, pr, fmaf(-gi, pi, Tr));
                Ti = fmaf(gr, pi, fmaf(gi, pr, Ti));
            }
            float ngr = fmaf(gr, gr, -gi * gi);
            gi = 2.f * gr * gi; gr = ngr;
        }
        float Er_ = __shfl_up(Tr, 1, 8);
        float Ei_ = __shfl_up(Ti, 1, 8);
        if (ss == 0) { Er_ = 0.f; Ei_ = 0.f; }
        __syncthreads();   // all Sf reads done; St overlays Sf
        // replay: write init states (fp16) directly, swizzled for B-fragments
        float Gr = Er_, Gi = Ei_;
        #pragma unroll
        for (int i = 0; i < 16; i++) {
            int c = ss * 16 + i;
            int sw = (c & 7) << 4;
            *(_Float16*)(St + c * 128 + ((sn * 2) ^ sw))        = (_Float16)Gr;
            *(_Float16*)(St + c * 128 + (((sn + 32) * 2) ^ sw)) = (_Float16)Gi;
            float nGr = fmaf(wTr, Gr, fmaf(-wTi, Gi, fr[i]));
            Gi = fmaf(wTr, Gi, fmaf(wTi, Gr, fi[i]));
            Gr = nGr;
        }
    }
    __syncthreads();

    // ---- GEMM2: Y[128 m][128 c] = Ktoe.U (K=128) + E.S (K=64) ----
    f32x4 acc[2][8];
    #pragma unroll
    for (int mi = 0; mi < 2; mi++)
        #pragma unroll
        for (int nt = 0; nt < 8; nt++) acc[mi][nt] = (f32x4){0.f, 0.f, 0.f, 0.f};
    #pragma unroll
    for (int mi = 0; mi < 2; mi++) {
        const _Float16* Arow = A2 + ((wave * 2 + mi) * 16 + rA) * 192;
        for (int ks = 0; ks < 4; ks++) {
            f16x8 af = *(const f16x8*)(Arow + ks * 32 + qA * 8);
            #pragma unroll
            for (int nt = 0; nt < 8; nt++) {
                int n = nt * 16 + rA;
                f16x8 bv = *(const f16x8*)(UT + n * 256 + ((ks * 64 + qA * 16) ^ ((n & 7) << 4)));
                acc[mi][nt] = MFMA16F(af, bv, acc[mi][nt]);
            }
        }
        #pragma unroll
        for (int ks2 = 0; ks2 < 2; ks2++) {
            f16x8 af = *(const f16x8*)(Arow + 128 + ks2 * 32 + qA * 8);
            #pragma unroll
            for (int nt = 0; nt < 8; nt++) {
                int c = nt * 16 + rA;
                f16x8 bv = *(const f16x8*)(St + c * 128 + ((ks2 * 64 + qA * 16) ^ ((c & 7) << 4)));
                acc[mi][nt] = MFMA16F(af, bv, acc[mi][nt]);
            }
        }
    }
    __syncthreads();   // all UT/St reads done; yst overlays

    // ---- epilogue: tanh -> yst fp16 [c][m], then coalesced f16x8 store ----
    #pragma unroll
    for (int mi = 0; mi < 2; mi++) {
        int m0 = (wave * 2 + mi) * 16 + qA * 4;
        #pragma unroll
        for (int nt = 0; nt < 8; nt++) {
            int c = nt * 16 + rA;
            f16x4 o;
            o[0] = (_Float16)fast_tanh(acc[mi][nt][0]);
            o[1] = (_Float16)fast_tanh(acc[mi][nt][1]);
            o[2] = (_Float16)fast_tanh(acc[mi][nt][2]);
            o[3] = (_Float16)fast_tanh(acc[mi][nt][3]);
            *(f16x4*)(yst + c * 272 + m0 * 2) = o;
        }
    }
    __syncthreads();
    for (int it = 0; it < 8; ++it) {
        int e = it * 256 + tid;      // 0..2047
        int c = e >> 4, l8 = e & 15;
        f16x8 hv = *(const f16x8*)(yst + c * 272 + l8 * 16);
        *(f16x8*)(uu + c * 128 + l8 * 8) = hv;
    }
}

// ---------------------------------------------------------------------------
// k_linear: MFMA channel-mix + tanh, fp16 in-place.
// ---------------------------------------------------------------------------
__global__ __launch_bounds__(256, 4)
void k_linear(_Float16* __restrict__ uio, const _Float16* __restrict__ W16,
              const float* __restrict__ bias) {
    __shared__ __align__(16) char lmem[33792];
    _Float16* Ul  = (_Float16*)lmem;     // [256 l][64 h], row 128 B, swizzled
    _Float16* yst = (_Float16*)lmem;     // [64 o][264 l] overlay after GEMM

    const int b   = blockIdx.y;
    const int l0  = blockIdx.x * 256;
    const int tid = threadIdx.x;
    const int lane = tid & 63;
    const int wave = tid >> 6;      // m-tile 0..3
    const int rA = lane & 15;
    const int qA = lane >> 4;

    _Float16* ub = uio + ((size_t)b << 20) + l0;

    for (int it = 0; it < 4; ++it) {
        int g  = it * 256 + tid;
        int hp = g >> 5;
        int l8 = g & 31;
        f16x8 v0 = *(const f16x8*)(ub + (size_t)(hp * 2)     * Lq + l8 * 8);
        f16x8 v1 = *(const f16x8*)(ub + (size_t)(hp * 2 + 1) * Lq + l8 * 8);
        const unsigned short* p0 = (const unsigned short*)&v0;
        const unsigned short* p1 = (const unsigned short*)&v1;
        int sw = (l8 & 7) << 4;
        #pragma unroll
        for (int j = 0; j < 8; j++) {
            unsigned int pk = (unsigned int)p0[j] | ((unsigned int)p1[j] << 16);
            *(unsigned int*)((char*)Ul + (l8 * 8 + j) * 128 + ((hp * 4) ^ sw)) = pk;
        }
    }
    __syncthreads();

    f32x4 acc[16];
    #pragma unroll
    for (int nt = 0; nt < 16; nt++) acc[nt] = (f32x4){0.f, 0.f, 0.f, 0.f};
    const _Float16* Wrow = W16 + (wave * 16 + rA) * 64;
    #pragma unroll
    for (int kf = 0; kf < 2; kf++) {
        f16x8 af = *(const f16x8*)(Wrow + kf * 32 + qA * 8);
        #pragma unroll
        for (int nt = 0; nt < 16; nt++) {
            int n = nt * 16 + rA;
            int sw = ((n >> 3) & 7) << 4;
            f16x8 bv = *(const f16x8*)((char*)Ul + n * 128 + ((kf * 64 + qA * 16) ^ sw));
            acc[nt] = MFMA16F(af, bv, acc[nt]);
        }
    }
    __syncthreads();

    {
        int ob = wave * 16 + qA * 4;
        float bo0 = bias[ob], bo1 = bias[ob + 1], bo2 = bias[ob + 2], bo3 = bias[ob + 3];
        #pragma unroll
        for (int nt = 0; nt < 16; nt++) {
            int l = nt * 16 + rA;
            yst[(ob + 0) * 264 + l] = (_Float16)fast_tanh(acc[nt][0] + bo0);
            yst[(ob + 1) * 264 + l] = (_Float16)fast_tanh(acc[nt][1] + bo1);
            yst[(ob + 2) * 264 + l] = (_Float16)fast_tanh(acc[nt][2] + bo2);
            yst[(ob + 3) * 264 + l] = (_Float16)fast_tanh(acc[nt][3] + bo3);
        }
    }
    __syncthreads();
    for (int it = 0; it < 8; ++it) {
        int e = it * 256 + tid;
        int o = e >> 5, l8 = e & 31;
        f16x8 hv = *(const f16x8*)(yst + o * 264 + l8 * 8);
        *(f16x8*)(ub + (size_t)o * Lq + l8 * 8) = hv;
    }
}

// ---------------------------------------------------------------------------
// k_out: out[b,l] = x[b,l] * 10^((sum_h w_out[h]*u16[b,h,l] + b_out)/20)
// ---------------------------------------------------------------------------
__global__ __launch_bounds__(256)
void k_out(const _Float16* __restrict__ u16, const float* __restrict__ x,
           const float* __restrict__ w_out, const float* __restrict__ b_out,
           float* __restrict__ out) {
    int idx = blockIdx.x * 256 + threadIdx.x;
    int b = idx >> 14;
    int l = idx & (Lq - 1);
    const _Float16* up = u16 + ((size_t)b << 20) + l;
    float acc = 0.f;
    #pragma unroll 8
    for (int hh = 0; hh < 64; ++hh)
        acc = fmaf(w_out[hh], (float)up[(size_t)hh << 14], acc);
    float g = acc + b_out[0];
    out[idx] = x[idx] * exp2f(g * 0.16609640474436812f);
}

// ---------------------------------------------------------------------------
extern "C" void kernel_launch(void* const* d_in, const int* in_sizes, int n_in,
                              void* d_out, int out_size, void* d_ws, size_t ws_size,
                              hipStream_t stream) {
    const float* x          = (const float*)d_in[0];
    const float* w_in       = (const float*)d_in[1];
    const float* b_in       = (const float*)d_in[2];
    const float* w_mid      = (const float*)d_in[3];
    const float* b_mid      = (const float*)d_in[4];
    const float* w_out      = (const float*)d_in[5];
    const float* b_out      = (const float*)d_in[6];
    const float* log_dt     = (const float*)d_in[7];
    const float* log_A_real = (const float*)d_in[8];
    const float* A_imag     = (const float*)d_in[9];
    const float* C_re       = (const float*)d_in[10];
    const float* C_im       = (const float*)d_in[11];
    const float* Dv         = (const float*)d_in[12];

    char* ws = (char*)d_ws;
    float*     wT_tab = (float*)(ws + WT_OFF_B);
    _Float16*  Wp     = (_Float16*)(ws + WP_OFF_B);
    _Float16*  A2     = (_Float16*)(ws + A2_OFF_B);
    _Float16*  W16    = (_Float16*)(ws + W16_OFF_B);
    _Float16*  u16    = (_Float16*)(ws + U_OFF_B);
    float* out = (float*)d_out;

    hipFuncSetAttribute((const void*)k_scan,
                        hipFuncAttributeMaxDynamicSharedMemorySize, SMEM_SZ);

    k_prep<<<NLAYERSq * Hq, 256, 0, stream>>>(log_dt, log_A_real, A_imag,
                                              C_re, C_im, Dv, w_mid,
                                              wT_tab, Wp, A2, W16);
    for (int layer = 0; layer < NLAYERSq; layer++) {
        if (layer > 0)
            k_linear<<<dim3(Lq / 256, Bq), 256, 0, stream>>>(
                u16, W16 + (size_t)(layer - 1) * Hq * Hq, b_mid + (size_t)(layer - 1) * Hq);
        k_scan<<<Bq * Hq, 256, SMEM_SZ, stream>>>(x, u16, Wp, A2, wT_tab, layer,
                                                  w_in, b_in);
    }
    k_out<<<(Bq * Lq) / 256, 256, 0, stream>>>(u16, x, w_out, b_out, out);
}